// Round 5
// baseline (523.115 us; speedup 1.0000x reference)
//
#include <hip/hip_runtime.h>
#include <math.h>

typedef unsigned short u16;
typedef unsigned int u32;
typedef __bf16 bf16x8 __attribute__((ext_vector_type(8)));
typedef float f32x4 __attribute__((ext_vector_type(4)));

#define MFMA16(a, b, c) __builtin_amdgcn_mfma_f32_16x16x32_bf16(a, b, c, 0, 0, 0)

// QSCALE = (1/sqrt(64)) * log2(e): folded into Q at projection time so the
// attention inner loop needs only v_exp_f32 (2^x).
#define QSCALE 0.1803368801111204f

typedef __attribute__((address_space(1))) void gvoid;
typedef __attribute__((address_space(3))) void lvoid;

__device__ __forceinline__ void gload_lds16(const void* g, void* l) {
    __builtin_amdgcn_global_load_lds((gvoid*)g, (lvoid*)l, 16, 0, 0);
}

__device__ __forceinline__ float fexp2(float x) {
#if __has_builtin(__builtin_amdgcn_exp2f)
    return __builtin_amdgcn_exp2f(x);
#else
    return __expf(x * 0.6931471805599453f);
#endif
}

__device__ __forceinline__ float b2f(u16 u) {
    union { u32 i; float f; } w;
    w.i = ((u32)u) << 16;
    return w.f;
}

__device__ __forceinline__ u16 f2b(float f) {
    union { float f; u32 i; } w;
    w.f = f;
    u32 x = w.i;
    u32 r = (x + 0x7fffu + ((x >> 16) & 1u)) >> 16;  // RNE
    return (u16)r;
}

__device__ __forceinline__ void unpack8(uint4 u, float* v) {
    v[0] = b2f((u16)(u.x & 0xffff)); v[1] = b2f((u16)(u.x >> 16));
    v[2] = b2f((u16)(u.y & 0xffff)); v[3] = b2f((u16)(u.y >> 16));
    v[4] = b2f((u16)(u.z & 0xffff)); v[5] = b2f((u16)(u.z >> 16));
    v[6] = b2f((u16)(u.w & 0xffff)); v[7] = b2f((u16)(u.w >> 16));
}

__device__ __forceinline__ u32 pack2(float a, float b) {
    return (u32)f2b(a) | ((u32)f2b(b) << 16);
}

// ---------------------------------------------------------------------------
// Input dtype detector: flag=1 -> fp32 inputs.
// ---------------------------------------------------------------------------
__global__ __launch_bounds__(256) void detect_k(const u32* __restrict__ x, int* __restrict__ flag)
{
    __shared__ int cnt[256];
    int c = 0;
#pragma unroll 4
    for (int i = 0; i < 256; ++i) {
        const u32 w = x[threadIdx.x * 256 + i];
        const u32 e = (w >> 7) & 0xFF;
        c += (e < 0x20 || e > 0x4F) ? 1 : 0;
    }
    cnt[threadIdx.x] = c;
    __syncthreads();
    if (threadIdx.x == 0) {
        int t = 0;
        for (int i = 0; i < 256; ++i) t += cnt[i];
        *flag = (t > 16384) ? 1 : 0;
    }
}

// Convert x and context in one dispatch: blockIdx.y selects tensor.
__global__ __launch_bounds__(256) void conv2_k(
    const void* __restrict__ a, const void* __restrict__ b,
    u16* __restrict__ oa, u16* __restrict__ ob, int n, const int* __restrict__ flag)
{
    const int f = *flag;
    const void* in = blockIdx.y ? b : a;
    u16* out = blockIdx.y ? ob : oa;
    const int i = (blockIdx.x * 256 + threadIdx.x) * 8;
    if (i >= n) return;
    if (f) {
        const float* p = (const float*)in + i;
        uint4 o;
        o.x = pack2(p[0], p[1]); o.y = pack2(p[2], p[3]);
        o.z = pack2(p[4], p[5]); o.w = pack2(p[6], p[7]);
        *(uint4*)(out + i) = o;
    } else {
        *(uint4*)(out + i) = *(const uint4*)((const u16*)in + i);
    }
}

struct PtrTab {
    const void* p[16];
    int off[16];
    int cnt[16];
};

__global__ __launch_bounds__(256) void conv_small_k(
    PtrTab t, u16* __restrict__ out, const int* __restrict__ flag)
{
    const int f = *flag;
    const void* src = t.p[blockIdx.x];
    const int n = t.cnt[blockIdx.x];
    u16* dst = out + t.off[blockIdx.x];
    for (int i = threadIdx.x; i < n; i += 256)
        dst[i] = f ? f2b(((const float*)src)[i]) : ((const u16*)src)[i];
}

// ---------------------------------------------------------------------------
// Generic transpose: in [rows][cols] -> out bf16 [cols][rows].
// ---------------------------------------------------------------------------
__global__ __launch_bounds__(256) void transpose_k(
    const void* __restrict__ in, u16* __restrict__ out, int rows, int cols,
    const int* __restrict__ flag)
{
    const int f = *flag;
    __shared__ u16 t[64][65];
    const int tid = threadIdx.x;
    const int lr = tid >> 4;
    const int lc = (tid & 15) * 4;
    const int r0 = blockIdx.y * 64, c0 = blockIdx.x * 64;
#pragma unroll
    for (int i = 0; i < 4; ++i) {
        const size_t off = (size_t)(r0 + i * 16 + lr) * cols + c0 + lc;
        if (f) {
            const float* p = (const float*)in + off;
            t[i * 16 + lr][lc + 0] = f2b(p[0]);
            t[i * 16 + lr][lc + 1] = f2b(p[1]);
            t[i * 16 + lr][lc + 2] = f2b(p[2]);
            t[i * 16 + lr][lc + 3] = f2b(p[3]);
        } else {
            const u16* p = (const u16*)in + off;
            t[i * 16 + lr][lc + 0] = p[0];
            t[i * 16 + lr][lc + 1] = p[1];
            t[i * 16 + lr][lc + 2] = p[2];
            t[i * 16 + lr][lc + 3] = p[3];
        }
    }
    __syncthreads();
#pragma unroll
    for (int i = 0; i < 4; ++i) {
        const int rr = i * 16 + lr;
        uint2 o;
        o.x = (u32)t[lc + 0][rr] | ((u32)t[lc + 1][rr] << 16);
        o.y = (u32)t[lc + 2][rr] | ((u32)t[lc + 3][rr] << 16);
        *(uint2*)(out + (size_t)(c0 + rr) * rows + r0 + lc) = o;
    }
}

// ---------------------------------------------------------------------------
// Fused transpose of the 6 head-blocked weights [16,1024,64] -> [1024,1024].
// grid (1, 16, 96): z = w*16 + h.
// ---------------------------------------------------------------------------
__global__ __launch_bounds__(256) void transpose6_k(
    PtrTab tab, u16* __restrict__ wT, const int* __restrict__ flag)
{
    const int f = *flag;
    __shared__ u16 t[64][65];
    const int tid = threadIdx.x;
    const int lr = tid >> 4;
    const int lc = (tid & 15) * 4;
    const int w = blockIdx.z >> 4, h = blockIdx.z & 15;
    const void* in = tab.p[w];
    u16* out = wT + (size_t)w * (1u << 20) + h * 65536;
    const size_t ibase = (size_t)h * 65536;
    const int r0 = blockIdx.y * 64;
#pragma unroll
    for (int i = 0; i < 4; ++i) {
        const size_t off = ibase + (size_t)(r0 + i * 16 + lr) * 64 + lc;
        if (f) {
            const float* p = (const float*)in + off;
            t[i * 16 + lr][lc + 0] = f2b(p[0]);
            t[i * 16 + lr][lc + 1] = f2b(p[1]);
            t[i * 16 + lr][lc + 2] = f2b(p[2]);
            t[i * 16 + lr][lc + 3] = f2b(p[3]);
        } else {
            const u16* p = (const u16*)in + off;
            t[i * 16 + lr][lc + 0] = p[0];
            t[i * 16 + lr][lc + 1] = p[1];
            t[i * 16 + lr][lc + 2] = p[2];
            t[i * 16 + lr][lc + 3] = p[3];
        }
    }
    __syncthreads();
#pragma unroll
    for (int i = 0; i < 4; ++i) {
        const int rr = i * 16 + lr;
        uint2 o;
        o.x = (u32)t[lc + 0][rr] | ((u32)t[lc + 1][rr] << 16);
        o.y = (u32)t[lc + 2][rr] | ((u32)t[lc + 3][rr] << 16);
        *(uint2*)(out + (size_t)rr * 1024 + r0 + lc) = o;
    }
}

// ---------------------------------------------------------------------------
// Grouped projection GEMM, BK=64 panelized, register-prefetch staging.
// M=4096, K=1024. grid (40, 32). SA-Q output pre-scaled by QSCALE (fp32).
// R3: (a) 2D XCD remap — each XCD owns a 20-bx x 8-by rectangle so A-slabs
//     are fetched by 1 XCD-pair-row instead of all 8 (FETCH model 81->~58MB);
// (b) LDS chunk XOR-swizzle (chunk ^= (row>>1)&3) on BOTH ds_write and
//     fragment ds_read (reg-staged path, rule-21-safe) — read conflicts
//     8-way -> 2-way (free per m136).
// ---------------------------------------------------------------------------
__global__ __launch_bounds__(256) void gemm_qkv_k(
    const u16* __restrict__ X, const u16* __restrict__ CTX,
    const u16* __restrict__ wT, const u16* __restrict__ bias,
    u16* __restrict__ Qo, u16* __restrict__ Ksa, u16* __restrict__ Vsa,
    u16* __restrict__ Kca, u16* __restrict__ Vca)
{
    __shared__ u16 sA[2][128 * 32];
    __shared__ u16 sB[2][128 * 32];
    const int tid = threadIdx.x;
    const int wave = tid >> 6;
    const int lane = tid & 63;

    // 2D XCD remap (bijective on 40x32): xcd=f&7 keeps the assumed id%8
    // XCD assignment; each xcd covers bx in [ (xcd&1)*20, +20 ), by in
    // [ (xcd>>1)*8, +8 ).
    const int f_id = blockIdx.y * 40 + blockIdx.x;
    const int xcd = f_id & 7;
    const int r_id = f_id >> 3;              // 0..159
    const int bx = (xcd & 1) * 20 + (r_id % 20);
    const int by = (xcd >> 1) * 8 + (r_id / 20);

    const int seg = bx >> 3, c8 = bx & 7;
    const int m0 = by * 128;
    const int wm = (wave >> 1) * 64;
    const int wn = (wave & 1) * 64;
    const u16* A = (seg < 3) ? X : CTX;

    const int lrow = lane >> 2;
    const int lcol = (lane & 3) * 8;
    const u16* gA = A + (size_t)(m0 + wave * 16 + lrow) * 1024 + lcol;
    const u16* gB = wT + (size_t)(bx * 128 + wave * 16 + lrow) * 1024 + lcol;
    const int lofs = wave * 16 * 32;
    // swizzled write chunk: row within buffer = wave*16+lrow; key=(row>>1)&3
    // == (lrow>>1)&3 since wave*16>>1 is 0 mod 4.
    const int wsw = lofs + lrow * 32 + (((lane & 3) ^ ((lrow >> 1) & 3)) * 8);

    u16* dA0 = &sA[0][wsw];
    u16* dA1 = &sA[1][wsw];
    u16* dA2 = &sA[0][64 * 32 + wsw];
    u16* dA3 = &sA[1][64 * 32 + wsw];
    u16* dB0 = &sB[0][wsw];
    u16* dB1 = &sB[1][wsw];
    u16* dB2 = &sB[0][64 * 32 + wsw];
    u16* dB3 = &sB[1][64 * 32 + wsw];

    uint4 rA0 = *(const uint4*)(gA);
    uint4 rA1 = *(const uint4*)(gA + 32);
    uint4 rA2 = *(const uint4*)(gA + (size_t)64 * 1024);
    uint4 rA3 = *(const uint4*)(gA + (size_t)64 * 1024 + 32);
    uint4 rB0 = *(const uint4*)(gB);
    uint4 rB1 = *(const uint4*)(gB + 32);
    uint4 rB2 = *(const uint4*)(gB + (size_t)64 * 1024);
    uint4 rB3 = *(const uint4*)(gB + (size_t)64 * 1024 + 32);

    f32x4 acc[4][4];
#pragma unroll
    for (int i = 0; i < 4; ++i)
#pragma unroll
        for (int j = 0; j < 4; ++j) acc[i][j] = (f32x4){0.f, 0.f, 0.f, 0.f};

    const int q15 = lane & 15;
    // swizzled read chunk: fragment row = wm + mt*16 + q15; key=(row>>1)&3
    // reduces to (q15>>1)&3 (wm and mt*16 contribute 0 mod 4 after >>1).
    const int koff = (((lane >> 4) ^ ((q15 >> 1) & 3)) * 8);

    for (int k0 = 0; k0 < 1024; k0 += 64) {
        __syncthreads();
        *(uint4*)dA0 = rA0; *(uint4*)dA1 = rA1;
        *(uint4*)dA2 = rA2; *(uint4*)dA3 = rA3;
        *(uint4*)dB0 = rB0; *(uint4*)dB1 = rB1;
        *(uint4*)dB2 = rB2; *(uint4*)dB3 = rB3;
        __syncthreads();
        if (k0 < 1024 - 64) {
            rA0 = *(const uint4*)(gA + k0 + 64);
            rA1 = *(const uint4*)(gA + k0 + 96);
            rA2 = *(const uint4*)(gA + (size_t)64 * 1024 + k0 + 64);
            rA3 = *(const uint4*)(gA + (size_t)64 * 1024 + k0 + 96);
            rB0 = *(const uint4*)(gB + k0 + 64);
            rB1 = *(const uint4*)(gB + k0 + 96);
            rB2 = *(const uint4*)(gB + (size_t)64 * 1024 + k0 + 64);
            rB3 = *(const uint4*)(gB + (size_t)64 * 1024 + k0 + 96);
        }
#pragma unroll 1
        for (int p = 0; p < 2; ++p) {
            bf16x8 af[4], bfr[4];
#pragma unroll
            for (int mt = 0; mt < 4; ++mt)
                af[mt] = *(const bf16x8*)(&sA[p][(wm + mt * 16 + q15) * 32 + koff]);
#pragma unroll
            for (int nt = 0; nt < 4; ++nt)
                bfr[nt] = *(const bf16x8*)(&sB[p][(wn + nt * 16 + q15) * 32 + koff]);
#pragma unroll
            for (int mt = 0; mt < 4; ++mt)
#pragma unroll
                for (int nt = 0; nt < 4; ++nt)
                    acc[mt][nt] = MFMA16(af[mt], bfr[nt], acc[mt][nt]);
        }
    }

    u16* outp;
    int vt;
    switch (seg) {
        case 0: outp = Qo;  vt = 0; break;
        case 1: outp = Ksa; vt = 0; break;
        case 2: outp = Vsa; vt = 1; break;
        case 3: outp = Kca; vt = 0; break;
        default: outp = Vca; vt = 1; break;
    }
    const float qs = (seg == 0) ? QSCALE : 1.0f;
    const int rq = (lane >> 4) * 4;
#pragma unroll
    for (int nt = 0; nt < 4; ++nt) {
        const int col = c8 * 128 + wn + nt * 16 + q15;
        const float bv = b2f(bias[bx * 128 + wn + nt * 16 + q15]);
#pragma unroll
        for (int mt = 0; mt < 4; ++mt) {
            const int row = m0 + wm + mt * 16 + rq;
            f32x4 v = acc[mt][nt];
            if (vt) {
                const int bb = row >> 10, tt = row & 1023;
                const int hh = col >> 6, rr = col & 63;
                const size_t idx = ((((size_t)bb * 16 + hh) * 64 + rr) << 10) + tt;
                uint2 o;
                o.x = pack2(v[0] + bv, v[1] + bv);
                o.y = pack2(v[2] + bv, v[3] + bv);
                *(uint2*)(outp + idx) = o;
            } else {
#pragma unroll
                for (int e = 0; e < 4; ++e)
                    outp[(size_t)(row + e) * 1024 + col] = f2b((v[e] + bv) * qs);
            }
        }
    }
}

// ===========================================================================
// 256x256 8-phase GEMM core (T2+T3+T4+T5 per learn_hip m194-m201/m218).
//   BM=BN=256, BK=64, 8 waves (2 M-groups x 4 N-groups), 512 threads.
//   LDS: 2 K-tile buffers x (A 256x64 + B 256x64) bf16 = 128 KiB.
//   Per K-tile: 4 phases, each {ds_read subtile | stage 1 half-tile} ->
//   s_barrier -> setprio(1) -> 16 MFMA -> setprio(0) -> s_barrier.
//   Counted vmcnt(4) once per K-tile; drained to 0 only at the last tiles.
//   Staging slot map (write-after-read-safe under the per-phase barriers):
//     B-half0(t+1) @ t.p1, B-half1(t+1) @ t.p2,
//     A-half0(t+2) @ t.p3, A-half1(t+2) @ t.p4.
//   Bank-conflict fix: chunk XOR-swizzle c ^= (row>>1)&3 applied on the
//   GLOBAL source address (gload_lds dest must stay linear) and identically
//   on the ds_read chunk -> conflict-free b128 reads (verified: 0 conflicts).
//   NOTE: only used at grids <= 256 blocks (1 block/CU) — at 320 blocks the
//   round quantization costs 1.6x (measured R1).
// ===========================================================================

#define BARR() asm volatile("s_barrier" ::: "memory")
#define VMW(N) do { asm volatile("s_waitcnt vmcnt(" #N ")" ::: "memory"); \
                    __builtin_amdgcn_sched_barrier(0); } while (0)

#define STG(ARR, GP, ROW0, T) do {                                         \
        const int b_ = (T) & 1; const int k_ = (T) * 64;                   \
        gload_lds16(GP + k_,      &ARR[b_][0][(ROW0) + wave * 16][0]);     \
        gload_lds16(GP + k_ + 32, &ARR[b_][1][(ROW0) + wave * 16][0]);     \
    } while (0)

#define LD_A(DST, ROWBASE)                                                        \
    _Pragma("unroll") for (int mf = 0; mf < 4; ++mf)                              \
    _Pragma("unroll") for (int kk = 0; kk < 2; ++kk)                              \
        DST[mf][kk] = *(const bf16x8*)&sA[buf][kk][(ROWBASE) + mf * 16 + q15][ksw];

#define LD_B(NB)                                                                  \
    _Pragma("unroll") for (int nf = 0; nf < 2; ++nf)                              \
    _Pragma("unroll") for (int kk = 0; kk < 2; ++kk)                              \
        bf[nf][kk] = *(const bf16x8*)&sB[buf][kk][wn64 + (NB) + nf * 16 + q15][ksw];

#define MFMA_PH(AF, MB, NB)                                                       \
    __builtin_amdgcn_s_setprio(1);                                                \
    _Pragma("unroll") for (int mf = 0; mf < 4; ++mf)                              \
    _Pragma("unroll") for (int nf = 0; nf < 2; ++nf)                              \
    _Pragma("unroll") for (int kk = 0; kk < 2; ++kk)                              \
        acc[(MB) + mf][(NB) + nf] =                                               \
            MFMA16(AF[mf][kk], bf[nf][kk], acc[(MB) + mf][(NB) + nf]);            \
    __builtin_amdgcn_s_setprio(0);

__device__ __forceinline__ void gemm8p_core(
    const u16* __restrict__ A, const u16* __restrict__ Bt,
    int ldK, int NT, int m0, int n0, f32x4 (&acc)[8][4])
{
    __shared__ u16 sA[2][2][256][32];   // [buf][kk-half][row][32 bf16] = 64 KiB
    __shared__ u16 sB[2][2][256][32];   // 64 KiB

    const int tid = threadIdx.x;
    const int wave = tid >> 6, lane = tid & 63;
    const int wave_m = wave >> 2;          // 0..1  (128 rows each)
    const int wave_n = wave & 3;           // 0..3  (64 cols each)
    const int q15 = lane & 15;
    const int wm128 = wave_m * 128;
    const int wn64 = wave_n * 64;
    // staging lane decomposition: 16 rows x 4 chunks of 16B per wave
    const int lrow = lane >> 2, lch = lane & 3;
    const int csw = (lch ^ ((lrow >> 1) & 3)) * 8;          // swizzled src chunk (u16)
    const int ksw = ((lane >> 4) ^ ((q15 >> 1) & 3)) * 8;   // swizzled read chunk (u16)

    const u16* gA0 = A + (size_t)(m0 + wave * 16 + lrow) * ldK + csw;
    const u16* gA1 = gA0 + (size_t)128 * ldK;
    const u16* gB0 = Bt + (size_t)(n0 + wave * 16 + lrow) * ldK + csw;
    const u16* gB1 = gB0 + (size_t)128 * ldK;

#pragma unroll
    for (int i = 0; i < 8; ++i)
#pragma unroll
        for (int j = 0; j < 4; ++j) acc[i][j] = (f32x4){0.f, 0.f, 0.f, 0.f};

    // ---- prologue: tile 0 fully + tile 1 A-halves ----
    STG(sA, gA0, 0, 0); STG(sA, gA1, 128, 0);
    STG(sB, gB0, 0, 0); STG(sB, gB1, 128, 0);
    if (NT > 1) {
        STG(sA, gA0, 0, 1); STG(sA, gA1, 128, 1);
        VMW(4);
    } else {
        VMW(0);
    }
    BARR();

    bf16x8 af0[4][2], af1[4][2], bf[2][2];

    for (int t = 0; t < NT; ++t) {
        const int buf = t & 1;
        // ---- phase 1: A rows [wm,wm+64) + B cols [wn,wn+32) ; stage B0(t+1)
        LD_A(af0, wm128);
        LD_B(0);
        if (t + 1 < NT) STG(sB, gB0, 0, t + 1);
        BARR();
        MFMA_PH(af0, 0, 0);
        BARR();
        // ---- phase 2: A rows [wm+64,wm+128) ; stage B1(t+1)
        LD_A(af1, wm128 + 64);
        if (t + 1 < NT) STG(sB, gB1, 128, t + 1);
        BARR();
        MFMA_PH(af1, 4, 0);
        BARR();
        // ---- phase 3: B cols [wn+32,wn+64) ; stage A0(t+2)
        LD_B(32);
        if (t + 2 < NT) STG(sA, gA0, 0, t + 2);
        BARR();
        MFMA_PH(af0, 0, 2);
        BARR();
        // ---- phase 4: stage A1(t+2) ; counted vmcnt at the tile boundary
        if (t + 2 < NT) {
            STG(sA, gA1, 128, t + 2);
            VMW(4);
        } else {
            VMW(0);
        }
        BARR();
        MFMA_PH(af1, 4, 2);
        BARR();
    }
}

// ---------------------------------------------------------------------------
// FFN1 on the 8-phase core: C = relu(A @ Bt^T + bias). M=4096, N=4096,
// K=1024. grid (16, 16) = 256 blocks exactly -> single round. 512 threads.
// ---------------------------------------------------------------------------
__global__ __launch_bounds__(512) void gemm8p_ffn1(
    const u16* __restrict__ A, const u16* __restrict__ Bt,
    const u16* __restrict__ bias, u16* __restrict__ C, int N, int NT)
{
    const int m0 = blockIdx.y * 256;
    const int n0 = blockIdx.x * 256;

    f32x4 acc[8][4];
    gemm8p_core(A, Bt, 1024, NT, m0, n0, acc);

    const int tid = threadIdx.x;
    const int wave = tid >> 6, lane = tid & 63;
    const int q15 = lane & 15;
    const int wm128 = (wave >> 2) * 128;
    const int wn64 = (wave & 3) * 64;
    const int rq = (lane >> 4) * 4;

#pragma unroll
    for (int nf = 0; nf < 4; ++nf) {
        const int col = n0 + wn64 + nf * 16 + q15;
        const float bv = b2f(bias[col]);
#pragma unroll
        for (int mf = 0; mf < 8; ++mf) {
            const int row = m0 + wm128 + mf * 16 + rq;
            f32x4 v = acc[mf][nf];
#pragma unroll
            for (int e = 0; e < 4; ++e)
                C[(size_t)(row + e) * N + col] = f2b(fmaxf(v[e] + bv, 0.f));
        }
    }
}

// ---------------------------------------------------------------------------
// FFN2 on the 8-phase core, split-K=3 (22/21/21 K-tiles), fp32 partials.
// M=4096, N=1024, K=4096. grid (4, 16, 3) = 192 blocks -> single round.
// z==0 adds bias.
// ---------------------------------------------------------------------------
__global__ __launch_bounds__(512) void gemm8p_ffn2(
    const u16* __restrict__ A, const u16* __restrict__ Bt,
    const u16* __restrict__ bias,
    float* __restrict__ P0, float* __restrict__ P1, float* __restrict__ P2)
{
    const int z = blockIdx.z;
    const int t0 = (z == 0) ? 0 : (22 + 21 * (z - 1));
    const int nt = (z == 0) ? 22 : 21;
    const int m0 = blockIdx.y * 256;
    const int n0 = blockIdx.x * 256;

    f32x4 acc[8][4];
    gemm8p_core(A + t0 * 64, Bt + t0 * 64, 4096, nt, m0, n0, acc);

    const int tid = threadIdx.x;
    const int wave = tid >> 6, lane = tid & 63;
    const int q15 = lane & 15;
    const int wm128 = (wave >> 2) * 128;
    const int wn64 = (wave & 3) * 64;
    const int rq = (lane >> 4) * 4;

    float* P = (z == 0) ? P0 : (z == 1) ? P1 : P2;
#pragma unroll
    for (int nf = 0; nf < 4; ++nf) {
        const int col = n0 + wn64 + nf * 16 + q15;
        const float bv = (z == 0) ? b2f(bias[col]) : 0.f;
#pragma unroll
        for (int mf = 0; mf < 8; ++mf) {
            const int row = m0 + wm128 + mf * 16 + rq;
            f32x4 v = acc[mf][nf];
#pragma unroll
            for (int e = 0; e < 4; ++e)
                P[(size_t)(row + e) * 1024 + col] = v[e] + bv;
        }
    }
}

// ---------------------------------------------------------------------------
// GEMM 64x128 tile, BK=64 panelized, global_load_lds staging (R8-verified).
// N=1024 shapes (K=1024). grid (M/64, 8). flags: 1=relu, 4=scale by QSCALE.
// ---------------------------------------------------------------------------
__global__ __launch_bounds__(256) void gemm_n1k(
    const u16* __restrict__ A, const u16* __restrict__ Bt,
    const u16* __restrict__ bias, const u16* __restrict__ resid,
    u16* __restrict__ C, int M, int N, int K, int flags)
{
    __shared__ u16 sA[2][64 * 32];
    __shared__ u16 sB[2][128 * 32];
    const int tid = threadIdx.x;
    const int wave = tid >> 6;
    const int lane = tid & 63;
    const int m0 = blockIdx.x * 64;
    const int n0 = blockIdx.y * 128;
    const int wm = (wave >> 1) * 32;
    const int wn = (wave & 1) * 64;

    const int lrow = lane >> 2;
    const int lcol = (lane & 3) * 8;
    const u16* gA = A + (size_t)(m0 + wave * 16 + lrow) * K + lcol;
    const u16* gB = Bt + (size_t)(n0 + wave * 32 + lrow) * K + lcol;
    const u16* gB2 = gB + (size_t)16 * K;
    const int lofsA = wave * 16 * 32;
    const int lofsB = wave * 32 * 32;

    f32x4 acc[2][4];
#pragma unroll
    for (int i = 0; i < 2; ++i)
#pragma unroll
        for (int j = 0; j < 4; ++j) acc[i][j] = (f32x4){0.f, 0.f, 0.f, 0.f};

    const int q15 = lane & 15;
    const int koff = (lane >> 4) * 8;

    for (int k0 = 0; k0 < K; k0 += 64) {
        __syncthreads();
        gload_lds16(gA + k0,      &sA[0][lofsA]);
        gload_lds16(gA + k0 + 32, &sA[1][lofsA]);
        gload_lds16(gB + k0,       &sB[0][lofsB]);
        gload_lds16(gB + k0 + 32,  &sB[1][lofsB]);
        gload_lds16(gB2 + k0,      &sB[0][lofsB + 16 * 32]);
        gload_lds16(gB2 + k0 + 32, &sB[1][lofsB + 16 * 32]);
        __syncthreads();
#pragma unroll 1
        for (int p = 0; p < 2; ++p) {
            bf16x8 af[2], bfr[4];
#pragma unroll
            for (int mt = 0; mt < 2; ++mt)
                af[mt] = *(const bf16x8*)(&sA[p][(wm + mt * 16 + q15) * 32 + koff]);
#pragma unroll
            for (int nt = 0; nt < 4; ++nt)
                bfr[nt] = *(const bf16x8*)(&sB[p][(wn + nt * 16 + q15) * 32 + koff]);
#pragma unroll
            for (int mt = 0; mt < 2; ++mt)
#pragma unroll
                for (int nt = 0; nt < 4; ++nt)
                    acc[mt][nt] = MFMA16(af[mt], bfr[nt], acc[mt][nt]);
        }
    }

    const int rq = (lane >> 4) * 4;
#pragma unroll
    for (int nt = 0; nt < 4; ++nt) {
        const int col = n0 + wn + nt * 16 + q15;
        const float bv = b2f(bias[col]);
#pragma unroll
        for (int mt = 0; mt < 2; ++mt) {
            const int row = m0 + wm + mt * 16 + rq;
            f32x4 v = acc[mt][nt];
#pragma unroll
            for (int e = 0; e < 4; ++e) {
                float val = v[e] + bv;
                if (flags & 1) val = fmaxf(val, 0.f);
                if (flags & 4) val *= QSCALE;
                const size_t o = (size_t)(row + e) * N + col;
                if (resid) val += b2f(resid[o]);
                C[o] = f2b(val);
            }
        }
    }
}

// ---------------------------------------------------------------------------
// Flash attention (no mask). Q,K: [B*S, H*R]; Vt: [B,H,R,S]; O: [B*S, H*R].
// grid 1024, flat id = qt*64 + (b*16+h). Rows padded to 72 (2-way aliasing).
// Q is pre-scaled by QSCALE at projection time, so P = exp2(QK) directly.
// ---------------------------------------------------------------------------
__global__ __launch_bounds__(256) void attn_k(
    const u16* __restrict__ Q, const u16* __restrict__ K,
    const u16* __restrict__ Vt, u16* __restrict__ O)
{
    __shared__ u16 sK[64 * 72];
    __shared__ u16 sV[64 * 72];
    __shared__ u16 sP[4][16 * 72];
    const int tid = threadIdx.x, wave = tid >> 6, lane = tid & 63;
    const int q15 = lane & 15, quad = lane >> 4;
    const int bid = blockIdx.x;
    const int g = bid & 63, qt = bid >> 6;
    const int h = g & 15, b = g >> 4;

    const u16* qb = Q + ((size_t)(b * 1024 + qt * 64 + wave * 16 + q15)) * 1024 + h * 64 + quad * 8;
    const bf16x8 qa0 = *(const bf16x8*)qb;
    const bf16x8 qa1 = *(const bf16x8*)(qb + 32);

    bf16x8 vone;
#pragma unroll
    for (int i = 0; i < 8; ++i) vone[i] = (__bf16)1.0f;

    f32x4 oacc[4];
#pragma unroll
    for (int i = 0; i < 4; ++i) oacc[i] = (f32x4){0.f, 0.f, 0.f, 0.f};
    f32x4 lacc = (f32x4){0.f, 0.f, 0.f, 0.f};

    const int srow = lane >> 3, scol8 = (lane & 7) * 8;
    const u16* kg = K + ((size_t)(b * 1024 + wave * 8 + srow)) * 1024 + h * 64 + scol8;
    const u16* vg = Vt + ((size_t)((b * 16 + h) * 64 + wave * 8 + srow)) * 1024 + scol8;
    u16* lKw = sK + (wave * 8 + srow) * 72 + scol8;
    u16* lVw = sV + (wave * 8 + srow) * 72 + scol8;

    uint4 k0r = *(const uint4*)kg;
    uint4 k1r = *(const uint4*)(kg + (size_t)32 * 1024);
    uint4 v0r = *(const uint4*)vg;
    uint4 v1r = *(const uint4*)(vg + (size_t)32 * 1024);

    for (int tt = 0; tt < 16; ++tt) {
        __syncthreads();
        *(uint4*)lKw = k0r;
        *(uint4*)(lKw + 32 * 72) = k1r;
        *(uint4*)lVw = v0r;
        *(uint4*)(lVw + 32 * 72) = v1r;
        __syncthreads();
        if (tt < 15) {
            const size_t t1 = (size_t)(tt + 1) * 64;
            k0r = *(const uint4*)(kg + t1 * 1024);
            k1r = *(const uint4*)(kg + t1 * 1024 + (size_t)32 * 1024);
            v0r = *(const uint4*)(vg + t1);
            v1r = *(const uint4*)(vg + t1 + (size_t)32 * 1024);
        }

        f32x4 sc[4];
#pragma unroll
        for (int nf = 0; nf < 4; ++nf) {
            bf16x8 kb0 = *(const bf16x8*)(sK + (nf * 16 + q15) * 72 + quad * 8);
            bf16x8 kb1 = *(const bf16x8*)(sK + (nf * 16 + q15) * 72 + 32 + quad * 8);
            f32x4 t = (f32x4){0.f, 0.f, 0.f, 0.f};
            t = MFMA16(qa0, kb0, t);
            t = MFMA16(qa1, kb1, t);
            sc[nf] = t;
        }
#pragma unroll
        for (int nf = 0; nf < 4; ++nf)
#pragma unroll
            for (int e = 0; e < 4; ++e) sc[nf][e] = fexp2(sc[nf][e]);
#pragma unroll
        for (int nf = 0; nf < 4; ++nf)
#pragma unroll
            for (int e = 0; e < 4; ++e)
                sP[wave][(quad * 4 + e) * 72 + nf * 16 + q15] = f2b(sc[nf][e]);
        asm volatile("s_waitcnt lgkmcnt(0)" ::: "memory");
        const bf16x8 pa0 = *(const bf16x8*)(sP[wave] + q15 * 72 + quad * 8);
        const bf16x8 pa1 = *(const bf16x8*)(sP[wave] + q15 * 72 + 32 + quad * 8);
#pragma unroll
        for (int rf = 0; rf < 4; ++rf) {
            bf16x8 vb0 = *(const bf16x8*)(sV + (rf * 16 + q15) * 72 + quad * 8);
            bf16x8 vb1 = *(const bf16x8*)(sV + (rf * 16 + q15) * 72 + 32 + quad * 8);
            oacc[rf] = MFMA16(pa0, vb0, oacc[rf]);
            oacc[rf] = MFMA16(pa1, vb1, oacc[rf]);
        }
        lacc = MFMA16(pa0, vone, lacc);
        lacc = MFMA16(pa1, vone, lacc);
    }
#pragma unroll
    for (int rf = 0; rf < 4; ++rf)
#pragma unroll
        for (int e = 0; e < 4; ++e) {
            const float v = oacc[rf][e] / lacc[e];
            const size_t row = (size_t)(b * 1024 + qt * 64 + wave * 16 + quad * 4 + e);
            O[row * 1024 + h * 64 + rf * 16 + q15] = f2b(v);
        }
}

// ---------------------------------------------------------------------------
// LayerNorm over last dim (1024), eps=1e-3. One wave/row, 4 rows/block.
// ---------------------------------------------------------------------------
__global__ __launch_bounds__(256) void ln_k(
    const u16* __restrict__ y, const u16* __restrict__ g,
    const u16* __restrict__ be, void* __restrict__ out, const int* __restrict__ oflag)
{
    const int f = oflag ? *oflag : 0;
    const int tid = threadIdx.x, wave = tid >> 6, lane = tid & 63;
    const size_t row = (size_t)blockIdx.x * 4 + wave;
    const u16* p = y + row * 1024 + lane * 16;
    uint4 u0 = *(const uint4*)p;
    uint4 u1 = *(const uint4*)(p + 8);
    float v[16];
    unpack8(u0, v);
    unpack8(u1, v + 8);
    float s = 0.f, s2 = 0.f;
#pragma unroll
    for (int i = 0; i < 16; ++i) { s += v[i]; s2 += v[i] * v[i]; }
#pragma unroll
    for (int off = 1; off < 64; off <<= 1) {
        s += __shfl_xor(s, off, 64);
        s2 += __shfl_xor(s2, off, 64);
    }
    const float mean = s * (1.f / 1024.f);
    const float var = s2 * (1.f / 1024.f) - mean * mean;
    const float rstd = rsqrtf(var + 1e-3f);
    uint4 g0 = *(const uint4*)(g + lane * 16);
    uint4 g1 = *(const uint4*)(g + lane * 16 + 8);
    uint4 b0 = *(const uint4*)(be + lane * 16);
    uint4 b1 = *(const uint4*)(be + lane * 16 + 8);
    float gv[16], bv[16];
    unpack8(g0, gv); unpack8(g1, gv + 8);
    unpack8(b0, bv); unpack8(b1, bv + 8);
    float w[16];
#pragma unroll
    for (int i = 0; i < 16; ++i) w[i] = (v[i] - mean) * rstd * gv[i] + bv[i];
    if (f) {
        float* q = (float*)out + row * 1024 + lane * 16;
#pragma unroll
        for (int i = 0; i < 16; i += 4)
            *(float4*)(q + i) = make_float4(w[i], w[i + 1], w[i + 2], w[i + 3]);
    } else {
        uint4 o0, o1;
        o0.x = pack2(w[0], w[1]);   o0.y = pack2(w[2], w[3]);
        o0.z = pack2(w[4], w[5]);   o0.w = pack2(w[6], w[7]);
        o1.x = pack2(w[8], w[9]);   o1.y = pack2(w[10], w[11]);
        o1.z = pack2(w[12], w[13]); o1.w = pack2(w[14], w[15]);
        u16* q = (u16*)out + row * 1024 + lane * 16;
        *(uint4*)q = o0;
        *(uint4*)(q + 8) = o1;
    }
}

// ---------------------------------------------------------------------------
// Fused split-K reduce (3 partials) + residual + LayerNorm -> d_out.
// ---------------------------------------------------------------------------
__global__ __launch_bounds__(256) void ln3f_k(
    const float* __restrict__ p0, const float* __restrict__ p1,
    const float* __restrict__ p2,
    const u16* __restrict__ resid, const u16* __restrict__ g,
    const u16* __restrict__ be, void* __restrict__ out, const int* __restrict__ oflag)
{
    const int f = *oflag;
    const int tid = threadIdx.x, wave = tid >> 6, lane = tid & 63;
    const size_t row = (size_t)blockIdx.x * 4 + wave;
    const size_t base = row * 1024 + lane * 16;
    float v[16];
#pragma unroll
    for (int i = 0; i < 16; i += 4) {
        float4 a = *(const float4*)(p0 + base + i);
        float4 b = *(const float4*)(p1 + base + i);
        float4 c = *(const float4*)(p2 + base + i);
        v[i + 0] = a.x + b.x + c.x; v[i + 1] = a.y + b.y + c.y;
        v[i + 2] = a.z + b.z + c.z; v[i + 3] = a.w + b.w + c.w;
    }
    uint4 r0 = *(const uint4*)(resid + base);
    uint4 r1 = *(const uint4*)(resid + base + 8);
    float rv[16];
    unpack8(r0, rv); unpack8(r1, rv + 8);
#pragma unroll
    for (int i = 0; i < 16; ++i) v[i] += rv[i];
    float s = 0.f, s2 = 0.f;
#pragma unroll
    for (int i = 0; i < 16; ++i) { s += v[i]; s2 += v[i] * v[i]; }
#pragma unroll
    for (int off = 1; off < 64; off <<= 1) {
        s += __shfl_xor(s, off, 64);
        s2 += __shfl_xor(s2, off, 64);
    }
    const float mean = s * (1.f / 1024.f);
    const float var = s2 * (1.f / 1024.f) - mean * mean;
    const float rstd = rsqrtf(var + 1e-3f);
    uint4 g0 = *(const uint4*)(g + lane * 16);
    uint4 g1 = *(const uint4*)(g + lane * 16 + 8);
    uint4 b0 = *(const uint4*)(be + lane * 16);
    uint4 b1 = *(const uint4*)(be + lane * 16 + 8);
    float gv[16], bv[16];
    unpack8(g0, gv); unpack8(g1, gv + 8);
    unpack8(b0, bv); unpack8(b1, bv + 8);
    float w[16];
#pragma unroll
    for (int i = 0; i < 16; ++i) w[i] = (v[i] - mean) * rstd * gv[i] + bv[i];
    if (f) {
        float* q = (float*)out + base;
#pragma unroll
        for (int i = 0; i < 16; i += 4)
            *(float4*)(q + i) = make_float4(w[i], w[i + 1], w[i + 2], w[i + 3]);
    } else {
        uint4 o0, o1;
        o0.x = pack2(w[0], w[1]);   o0.y = pack2(w[2], w[3]);
        o0.z = pack2(w[4], w[5]);   o0.w = pack2(w[6], w[7]);
        o1.x = pack2(w[8], w[9]);   o1.y = pack2(w[10], w[11]);
        o1.z = pack2(w[12], w[13]); o1.w = pack2(w[14], w[15]);
        u16* q = (u16*)out + base;
        *(uint4*)q = o0;
        *(uint4*)(q + 8) = o1;
    }
}

// ---------------------------------------------------------------------------
extern "C" void kernel_launch(void* const* d_in, const int* in_sizes, int n_in,
                              void* d_out, int out_size, void* d_ws, size_t ws_size,
                              hipStream_t stream)
{
    (void)in_sizes; (void)n_in; (void)out_size; (void)ws_size;
    const void* x   = d_in[0];
    const void* ctx = d_in[1];

    u16* ws = (u16*)d_ws;
    const size_t MEG = 1u << 20;
    u16* wT      = ws;               // 0..16M elems: transposed weights
    u16* bufx    = ws + 16 * MEG;
    u16* bufctx  = ws + 20 * MEG;
    u16* bufq    = ws + 24 * MEG;
    u16* bufk_sa = ws + 28 * MEG;
    u16* bufvt_sa= ws + 32 * MEG;
    u16* bufk_ca = ws + 36 * MEG;
    u16* bufvt_ca= ws + 40 * MEG;
    u16* bufo    = ws + 44 * MEG;
    u16* bufln   = ws + 48 * MEG;
    u16* small   = ws + 52 * MEG;
    int* flag    = (int*)(small + 20480);
    u16* bufh    = ws + 16 * MEG;    // FFN hidden (16..32M; bufx/ctx/q/k_sa dead)
    // split-K=3 fp32 partials (each 4096x1024 f32 = 16 MB = 8M u16):
    //  p0: 32..40M (bufvt_sa dead), p1: 40..48M (bufvt_ca/bufo dead),
    //  p2: 4..12M (wT[4..12M] all consumed before FFN2; wT[12..16M] stays live)
    float* part0 = (float*)(ws + 32 * MEG);
    float* part1 = (float*)(ws + 40 * MEG);
    float* part2 = (float*)(ws + 4 * MEG);

    const int O_SABQ = 0,    O_SABK = 1024, O_SABV = 2048;
    const int O_CABK = 3072, O_CABV = 4096, O_CABQ = 5120;
    const int O_SABO = 6144, O_CABO = 7168;
    const int O_L1G = 8192,  O_L1B = 9216,  O_L2G = 10240, O_L2B = 11264;
    const int O_L3G = 12288, O_L3B = 13312, O_FB1 = 14336, O_FB2 = 18432;

    PtrTab tab;
    const void* sp[16] = { d_in[3], d_in[5], d_in[7], d_in[13], d_in[15], d_in[11],
                           d_in[9], d_in[17],
                           d_in[18], d_in[19], d_in[20], d_in[21], d_in[22], d_in[23],
                           d_in[25], d_in[27] };
    const int so[16] = { O_SABQ, O_SABK, O_SABV, O_CABK, O_CABV, O_CABQ, O_SABO, O_CABO,
                         O_L1G, O_L1B, O_L2G, O_L2B, O_L3G, O_L3B, O_FB1, O_FB2 };
    const int sc[16] = { 1024, 1024, 1024, 1024, 1024, 1024, 1024, 1024,
                         1024, 1024, 1024, 1024, 1024, 1024, 4096, 1024 };
    for (int i = 0; i < 16; ++i) { tab.p[i] = sp[i]; tab.off[i] = so[i]; tab.cnt[i] = sc[i]; }

    PtrTab tab6;
    const void* wp[6] = { d_in[2], d_in[4], d_in[6], d_in[12], d_in[14], d_in[10] };
    for (int i = 0; i < 6; ++i) tab6.p[i] = wp[i];

    const dim3 blk(256);
    const dim3 blk8(512);
    const dim3 gN1(64, 8);

    // ---- dtype normalize + weight prep (R6-verified chain) ----
    detect_k<<<1, blk, 0, stream>>>((const u32*)x, flag);
    conv2_k<<<dim3(2048, 2), blk, 0, stream>>>(x, ctx, bufx, bufctx, 4 * MEG, flag);
    conv_small_k<<<dim3(16), blk, 0, stream>>>(tab, small, flag);
    transpose6_k<<<dim3(1, 16, 96), blk, 0, stream>>>(tab6, wT, flag);
    transpose_k<<<dim3(16, 16), blk, 0, stream>>>(d_in[8],  wT + 6 * MEG, 1024, 1024, flag);
    transpose_k<<<dim3(16, 16), blk, 0, stream>>>(d_in[16], wT + 7 * MEG, 1024, 1024, flag);
    transpose_k<<<dim3(64, 16), blk, 0, stream>>>(d_in[24], wT + 8 * MEG, 1024, 4096, flag);
    transpose_k<<<dim3(16, 64), blk, 0, stream>>>(d_in[26], wT + 12 * MEG, 4096, 1024, flag);

    // ---- fused projections (SA-Q pre-scaled by QSCALE) ----
    gemm_qkv_k<<<dim3(40, 32), blk, 0, stream>>>(bufx, bufctx, wT, small,
                                                 bufq, bufk_sa, bufvt_sa, bufk_ca, bufvt_ca);

    // ---- self-attention ----
    attn_k<<<dim3(1024), blk, 0, stream>>>(bufq, bufk_sa, bufvt_sa, bufo);
    gemm_n1k<<<gN1, blk, 0, stream>>>(bufo, wT + 6 * MEG, small + O_SABO, bufx,
                                      bufq, 4096, 1024, 1024, 0);
    ln_k<<<dim3(1024), blk, 0, stream>>>(bufq, small + O_L1G, small + O_L1B, bufln, nullptr);

    // ---- cross-attention (CA-Q pre-scaled via flags|4) ----
    gemm_n1k<<<gN1, blk, 0, stream>>>(bufln, wT + 5 * MEG, small + O_CABQ, nullptr,
                                      bufq, 4096, 1024, 1024, 4);
    attn_k<<<dim3(1024), blk, 0, stream>>>(bufq, bufk_ca, bufvt_ca, bufo);
    gemm_n1k<<<gN1, blk, 0, stream>>>(bufo, wT + 7 * MEG, small + O_CABO, bufln,
                                      bufq, 4096, 1024, 1024, 0);
    ln_k<<<dim3(1024), blk, 0, stream>>>(bufq, small + O_L2G, small + O_L2B, bufln, nullptr);

    // ---- FFN (256^2 8-phase; FFN2 split-K=3 + fused reduce/LN) ----
    gemm8p_ffn1<<<dim3(16, 16), blk8, 0, stream>>>(bufln, wT + 8 * MEG, small + O_FB1,
                                                   bufh, 4096, 16);
    gemm8p_ffn2<<<dim3(4, 16, 3), blk8, 0, stream>>>(bufh, wT + 12 * MEG, small + O_FB2,
                                                     part0, part1, part2);
    ln3f_k<<<dim3(1024), blk, 0, stream>>>(part0, part1, part2, bufln,
                                           small + O_L3G, small + O_L3B, d_out, flag);
}

// Round 6
// 520.363 us; speedup vs baseline: 1.0053x; 1.0053x over previous
//
#include <hip/hip_runtime.h>
#include <math.h>

typedef unsigned short u16;
typedef unsigned int u32;
typedef __bf16 bf16x8 __attribute__((ext_vector_type(8)));
typedef float f32x4 __attribute__((ext_vector_type(4)));

#define MFMA16(a, b, c) __builtin_amdgcn_mfma_f32_16x16x32_bf16(a, b, c, 0, 0, 0)

// QSCALE = (1/sqrt(64)) * log2(e): folded into Q at projection time so the
// attention inner loop needs only v_exp_f32 (2^x).
#define QSCALE 0.1803368801111204f

typedef __attribute__((address_space(1))) void gvoid;
typedef __attribute__((address_space(3))) void lvoid;

__device__ __forceinline__ void gload_lds16(const void* g, void* l) {
    __builtin_amdgcn_global_load_lds((gvoid*)g, (lvoid*)l, 16, 0, 0);
}

__device__ __forceinline__ float fexp2(float x) {
#if __has_builtin(__builtin_amdgcn_exp2f)
    return __builtin_amdgcn_exp2f(x);
#else
    return __expf(x * 0.6931471805599453f);
#endif
}

__device__ __forceinline__ float b2f(u16 u) {
    union { u32 i; float f; } w;
    w.i = ((u32)u) << 16;
    return w.f;
}

__device__ __forceinline__ u16 f2b(float f) {
    union { float f; u32 i; } w;
    w.f = f;
    u32 x = w.i;
    u32 r = (x + 0x7fffu + ((x >> 16) & 1u)) >> 16;  // RNE
    return (u16)r;
}

__device__ __forceinline__ void unpack8(uint4 u, float* v) {
    v[0] = b2f((u16)(u.x & 0xffff)); v[1] = b2f((u16)(u.x >> 16));
    v[2] = b2f((u16)(u.y & 0xffff)); v[3] = b2f((u16)(u.y >> 16));
    v[4] = b2f((u16)(u.z & 0xffff)); v[5] = b2f((u16)(u.z >> 16));
    v[6] = b2f((u16)(u.w & 0xffff)); v[7] = b2f((u16)(u.w >> 16));
}

__device__ __forceinline__ u32 pack2(float a, float b) {
    return (u32)f2b(a) | ((u32)f2b(b) << 16);
}

// ---------------------------------------------------------------------------
// Input dtype detector: flag=1 -> fp32 inputs.
// ---------------------------------------------------------------------------
__global__ __launch_bounds__(256) void detect_k(const u32* __restrict__ x, int* __restrict__ flag)
{
    __shared__ int cnt[256];
    int c = 0;
#pragma unroll 4
    for (int i = 0; i < 256; ++i) {
        const u32 w = x[threadIdx.x * 256 + i];
        const u32 e = (w >> 7) & 0xFF;
        c += (e < 0x20 || e > 0x4F) ? 1 : 0;
    }
    cnt[threadIdx.x] = c;
    __syncthreads();
    if (threadIdx.x == 0) {
        int t = 0;
        for (int i = 0; i < 256; ++i) t += cnt[i];
        *flag = (t > 16384) ? 1 : 0;
    }
}

// Convert x and context in one dispatch: blockIdx.y selects tensor.
__global__ __launch_bounds__(256) void conv2_k(
    const void* __restrict__ a, const void* __restrict__ b,
    u16* __restrict__ oa, u16* __restrict__ ob, int n, const int* __restrict__ flag)
{
    const int f = *flag;
    const void* in = blockIdx.y ? b : a;
    u16* out = blockIdx.y ? ob : oa;
    const int i = (blockIdx.x * 256 + threadIdx.x) * 8;
    if (i >= n) return;
    if (f) {
        const float* p = (const float*)in + i;
        uint4 o;
        o.x = pack2(p[0], p[1]); o.y = pack2(p[2], p[3]);
        o.z = pack2(p[4], p[5]); o.w = pack2(p[6], p[7]);
        *(uint4*)(out + i) = o;
    } else {
        *(uint4*)(out + i) = *(const uint4*)((const u16*)in + i);
    }
}

struct PtrTab {
    const void* p[16];
    int off[16];
    int cnt[16];
};

__global__ __launch_bounds__(256) void conv_small_k(
    PtrTab t, u16* __restrict__ out, const int* __restrict__ flag)
{
    const int f = *flag;
    const void* src = t.p[blockIdx.x];
    const int n = t.cnt[blockIdx.x];
    u16* dst = out + t.off[blockIdx.x];
    for (int i = threadIdx.x; i < n; i += 256)
        dst[i] = f ? f2b(((const float*)src)[i]) : ((const u16*)src)[i];
}

// ---------------------------------------------------------------------------
// Generic transpose: in [rows][cols] -> out bf16 [cols][rows].
// ---------------------------------------------------------------------------
__global__ __launch_bounds__(256) void transpose_k(
    const void* __restrict__ in, u16* __restrict__ out, int rows, int cols,
    const int* __restrict__ flag)
{
    const int f = *flag;
    __shared__ u16 t[64][65];
    const int tid = threadIdx.x;
    const int lr = tid >> 4;
    const int lc = (tid & 15) * 4;
    const int r0 = blockIdx.y * 64, c0 = blockIdx.x * 64;
#pragma unroll
    for (int i = 0; i < 4; ++i) {
        const size_t off = (size_t)(r0 + i * 16 + lr) * cols + c0 + lc;
        if (f) {
            const float* p = (const float*)in + off;
            t[i * 16 + lr][lc + 0] = f2b(p[0]);
            t[i * 16 + lr][lc + 1] = f2b(p[1]);
            t[i * 16 + lr][lc + 2] = f2b(p[2]);
            t[i * 16 + lr][lc + 3] = f2b(p[3]);
        } else {
            const u16* p = (const u16*)in + off;
            t[i * 16 + lr][lc + 0] = p[0];
            t[i * 16 + lr][lc + 1] = p[1];
            t[i * 16 + lr][lc + 2] = p[2];
            t[i * 16 + lr][lc + 3] = p[3];
        }
    }
    __syncthreads();
#pragma unroll
    for (int i = 0; i < 4; ++i) {
        const int rr = i * 16 + lr;
        uint2 o;
        o.x = (u32)t[lc + 0][rr] | ((u32)t[lc + 1][rr] << 16);
        o.y = (u32)t[lc + 2][rr] | ((u32)t[lc + 3][rr] << 16);
        *(uint2*)(out + (size_t)(c0 + rr) * rows + r0 + lc) = o;
    }
}

// ---------------------------------------------------------------------------
// Fused transpose of the 6 head-blocked weights [16,1024,64] -> [1024,1024].
// grid (1, 16, 96): z = w*16 + h.
// ---------------------------------------------------------------------------
__global__ __launch_bounds__(256) void transpose6_k(
    PtrTab tab, u16* __restrict__ wT, const int* __restrict__ flag)
{
    const int f = *flag;
    __shared__ u16 t[64][65];
    const int tid = threadIdx.x;
    const int lr = tid >> 4;
    const int lc = (tid & 15) * 4;
    const int w = blockIdx.z >> 4, h = blockIdx.z & 15;
    const void* in = tab.p[w];
    u16* out = wT + (size_t)w * (1u << 20) + h * 65536;
    const size_t ibase = (size_t)h * 65536;
    const int r0 = blockIdx.y * 64;
#pragma unroll
    for (int i = 0; i < 4; ++i) {
        const size_t off = ibase + (size_t)(r0 + i * 16 + lr) * 64 + lc;
        if (f) {
            const float* p = (const float*)in + off;
            t[i * 16 + lr][lc + 0] = f2b(p[0]);
            t[i * 16 + lr][lc + 1] = f2b(p[1]);
            t[i * 16 + lr][lc + 2] = f2b(p[2]);
            t[i * 16 + lr][lc + 3] = f2b(p[3]);
        } else {
            const u16* p = (const u16*)in + off;
            t[i * 16 + lr][lc + 0] = p[0];
            t[i * 16 + lr][lc + 1] = p[1];
            t[i * 16 + lr][lc + 2] = p[2];
            t[i * 16 + lr][lc + 3] = p[3];
        }
    }
    __syncthreads();
#pragma unroll
    for (int i = 0; i < 4; ++i) {
        const int rr = i * 16 + lr;
        uint2 o;
        o.x = (u32)t[lc + 0][rr] | ((u32)t[lc + 1][rr] << 16);
        o.y = (u32)t[lc + 2][rr] | ((u32)t[lc + 3][rr] << 16);
        *(uint2*)(out + (size_t)rr * 1024 + r0 + lc) = o;
    }
}

// ---------------------------------------------------------------------------
// Grouped projection GEMM, BK=64 panelized, register-prefetch staging.
// M=4096, K=1024. grid (40, 32). SA-Q output pre-scaled by QSCALE (fp32).
// R5 verdicts: LDS chunk XOR-swizzle KEPT (conflicts 5.24M->0, -2us);
// 2D XCD remap REVERTED (FETCH rose 81->90.5MB — remap theory refuted).
// ---------------------------------------------------------------------------
__global__ __launch_bounds__(256) void gemm_qkv_k(
    const u16* __restrict__ X, const u16* __restrict__ CTX,
    const u16* __restrict__ wT, const u16* __restrict__ bias,
    u16* __restrict__ Qo, u16* __restrict__ Ksa, u16* __restrict__ Vsa,
    u16* __restrict__ Kca, u16* __restrict__ Vca)
{
    __shared__ u16 sA[2][128 * 32];
    __shared__ u16 sB[2][128 * 32];
    const int tid = threadIdx.x;
    const int wave = tid >> 6;
    const int lane = tid & 63;

    const int bx = blockIdx.x;
    const int by = blockIdx.y;

    const int seg = bx >> 3, c8 = bx & 7;
    const int m0 = by * 128;
    const int wm = (wave >> 1) * 64;
    const int wn = (wave & 1) * 64;
    const u16* A = (seg < 3) ? X : CTX;

    const int lrow = lane >> 2;
    const int lcol = (lane & 3) * 8;
    const u16* gA = A + (size_t)(m0 + wave * 16 + lrow) * 1024 + lcol;
    const u16* gB = wT + (size_t)(bx * 128 + wave * 16 + lrow) * 1024 + lcol;
    const int lofs = wave * 16 * 32;
    // swizzled write chunk: row within buffer = wave*16+lrow; key=(row>>1)&3
    // == (lrow>>1)&3 since wave*16>>1 is 0 mod 4.
    const int wsw = lofs + lrow * 32 + (((lane & 3) ^ ((lrow >> 1) & 3)) * 8);

    u16* dA0 = &sA[0][wsw];
    u16* dA1 = &sA[1][wsw];
    u16* dA2 = &sA[0][64 * 32 + wsw];
    u16* dA3 = &sA[1][64 * 32 + wsw];
    u16* dB0 = &sB[0][wsw];
    u16* dB1 = &sB[1][wsw];
    u16* dB2 = &sB[0][64 * 32 + wsw];
    u16* dB3 = &sB[1][64 * 32 + wsw];

    uint4 rA0 = *(const uint4*)(gA);
    uint4 rA1 = *(const uint4*)(gA + 32);
    uint4 rA2 = *(const uint4*)(gA + (size_t)64 * 1024);
    uint4 rA3 = *(const uint4*)(gA + (size_t)64 * 1024 + 32);
    uint4 rB0 = *(const uint4*)(gB);
    uint4 rB1 = *(const uint4*)(gB + 32);
    uint4 rB2 = *(const uint4*)(gB + (size_t)64 * 1024);
    uint4 rB3 = *(const uint4*)(gB + (size_t)64 * 1024 + 32);

    f32x4 acc[4][4];
#pragma unroll
    for (int i = 0; i < 4; ++i)
#pragma unroll
        for (int j = 0; j < 4; ++j) acc[i][j] = (f32x4){0.f, 0.f, 0.f, 0.f};

    const int q15 = lane & 15;
    // swizzled read chunk: fragment row = wm + mt*16 + q15; key=(row>>1)&3
    // reduces to (q15>>1)&3 (wm and mt*16 contribute 0 mod 4 after >>1).
    const int koff = (((lane >> 4) ^ ((q15 >> 1) & 3)) * 8);

    for (int k0 = 0; k0 < 1024; k0 += 64) {
        __syncthreads();
        *(uint4*)dA0 = rA0; *(uint4*)dA1 = rA1;
        *(uint4*)dA2 = rA2; *(uint4*)dA3 = rA3;
        *(uint4*)dB0 = rB0; *(uint4*)dB1 = rB1;
        *(uint4*)dB2 = rB2; *(uint4*)dB3 = rB3;
        __syncthreads();
        if (k0 < 1024 - 64) {
            rA0 = *(const uint4*)(gA + k0 + 64);
            rA1 = *(const uint4*)(gA + k0 + 96);
            rA2 = *(const uint4*)(gA + (size_t)64 * 1024 + k0 + 64);
            rA3 = *(const uint4*)(gA + (size_t)64 * 1024 + k0 + 96);
            rB0 = *(const uint4*)(gB + k0 + 64);
            rB1 = *(const uint4*)(gB + k0 + 96);
            rB2 = *(const uint4*)(gB + (size_t)64 * 1024 + k0 + 64);
            rB3 = *(const uint4*)(gB + (size_t)64 * 1024 + k0 + 96);
        }
#pragma unroll 1
        for (int p = 0; p < 2; ++p) {
            bf16x8 af[4], bfr[4];
#pragma unroll
            for (int mt = 0; mt < 4; ++mt)
                af[mt] = *(const bf16x8*)(&sA[p][(wm + mt * 16 + q15) * 32 + koff]);
#pragma unroll
            for (int nt = 0; nt < 4; ++nt)
                bfr[nt] = *(const bf16x8*)(&sB[p][(wn + nt * 16 + q15) * 32 + koff]);
#pragma unroll
            for (int mt = 0; mt < 4; ++mt)
#pragma unroll
                for (int nt = 0; nt < 4; ++nt)
                    acc[mt][nt] = MFMA16(af[mt], bfr[nt], acc[mt][nt]);
        }
    }

    u16* outp;
    int vt;
    switch (seg) {
        case 0: outp = Qo;  vt = 0; break;
        case 1: outp = Ksa; vt = 0; break;
        case 2: outp = Vsa; vt = 1; break;
        case 3: outp = Kca; vt = 0; break;
        default: outp = Vca; vt = 1; break;
    }
    const float qs = (seg == 0) ? QSCALE : 1.0f;
    const int rq = (lane >> 4) * 4;
#pragma unroll
    for (int nt = 0; nt < 4; ++nt) {
        const int col = c8 * 128 + wn + nt * 16 + q15;
        const float bv = b2f(bias[bx * 128 + wn + nt * 16 + q15]);
#pragma unroll
        for (int mt = 0; mt < 4; ++mt) {
            const int row = m0 + wm + mt * 16 + rq;
            f32x4 v = acc[mt][nt];
            if (vt) {
                const int bb = row >> 10, tt = row & 1023;
                const int hh = col >> 6, rr = col & 63;
                const size_t idx = ((((size_t)bb * 16 + hh) * 64 + rr) << 10) + tt;
                uint2 o;
                o.x = pack2(v[0] + bv, v[1] + bv);
                o.y = pack2(v[2] + bv, v[3] + bv);
                *(uint2*)(outp + idx) = o;
            } else {
#pragma unroll
                for (int e = 0; e < 4; ++e)
                    outp[(size_t)(row + e) * 1024 + col] = f2b((v[e] + bv) * qs);
            }
        }
    }
}

// ===========================================================================
// 256x256 8-phase GEMM core (T2+T3+T4+T5 per learn_hip m194-m201/m218).
//   BM=BN=256, BK=64, 8 waves (2 M-groups x 4 N-groups), 512 threads.
//   LDS: 2 K-tile buffers x (A 256x64 + B 256x64) bf16 = 128 KiB.
//   Per K-tile: 4 phases, each {ds_read subtile | stage 1 half-tile} ->
//   s_barrier -> setprio(1) -> 16 MFMA -> setprio(0) -> s_barrier.
//   Counted vmcnt(4) once per K-tile; drained to 0 only at the last tiles.
//   Staging slot map (write-after-read-safe under the per-phase barriers):
//     B-half0(t+1) @ t.p1, B-half1(t+1) @ t.p2,
//     A-half0(t+2) @ t.p3, A-half1(t+2) @ t.p4.
//   Bank-conflict fix: chunk XOR-swizzle c ^= (row>>1)&3 applied on the
//   GLOBAL source address (gload_lds dest must stay linear) and identically
//   on the ds_read chunk -> conflict-free b128 reads (verified: 0 conflicts).
//   NOTE: only used at grids <= 256 blocks (1 block/CU) — at 320 blocks the
//   round quantization costs 1.6x (measured R1).
// ===========================================================================

#define BARR() asm volatile("s_barrier" ::: "memory")
#define VMW(N) do { asm volatile("s_waitcnt vmcnt(" #N ")" ::: "memory"); \
                    __builtin_amdgcn_sched_barrier(0); } while (0)

#define STG(ARR, GP, ROW0, T) do {                                         \
        const int b_ = (T) & 1; const int k_ = (T) * 64;                   \
        gload_lds16(GP + k_,      &ARR[b_][0][(ROW0) + wave * 16][0]);     \
        gload_lds16(GP + k_ + 32, &ARR[b_][1][(ROW0) + wave * 16][0]);     \
    } while (0)

#define LD_A(DST, ROWBASE)                                                        \
    _Pragma("unroll") for (int mf = 0; mf < 4; ++mf)                              \
    _Pragma("unroll") for (int kk = 0; kk < 2; ++kk)                              \
        DST[mf][kk] = *(const bf16x8*)&sA[buf][kk][(ROWBASE) + mf * 16 + q15][ksw];

#define LD_B(NB)                                                                  \
    _Pragma("unroll") for (int nf = 0; nf < 2; ++nf)                              \
    _Pragma("unroll") for (int kk = 0; kk < 2; ++kk)                              \
        bf[nf][kk] = *(const bf16x8*)&sB[buf][kk][wn64 + (NB) + nf * 16 + q15][ksw];

#define MFMA_PH(AF, MB, NB)                                                       \
    __builtin_amdgcn_s_setprio(1);                                                \
    _Pragma("unroll") for (int mf = 0; mf < 4; ++mf)                              \
    _Pragma("unroll") for (int nf = 0; nf < 2; ++nf)                              \
    _Pragma("unroll") for (int kk = 0; kk < 2; ++kk)                              \
        acc[(MB) + mf][(NB) + nf] =                                               \
            MFMA16(AF[mf][kk], bf[nf][kk], acc[(MB) + mf][(NB) + nf]);            \
    __builtin_amdgcn_s_setprio(0);

__device__ __forceinline__ void gemm8p_core(
    const u16* __restrict__ A, const u16* __restrict__ Bt,
    int ldK, int NT, int m0, int n0, f32x4 (&acc)[8][4])
{
    __shared__ u16 sA[2][2][256][32];   // [buf][kk-half][row][32 bf16] = 64 KiB
    __shared__ u16 sB[2][2][256][32];   // 64 KiB

    const int tid = threadIdx.x;
    const int wave = tid >> 6, lane = tid & 63;
    const int wave_m = wave >> 2;          // 0..1  (128 rows each)
    const int wave_n = wave & 3;           // 0..3  (64 cols each)
    const int q15 = lane & 15;
    const int wm128 = wave_m * 128;
    const int wn64 = wave_n * 64;
    // staging lane decomposition: 16 rows x 4 chunks of 16B per wave
    const int lrow = lane >> 2, lch = lane & 3;
    const int csw = (lch ^ ((lrow >> 1) & 3)) * 8;          // swizzled src chunk (u16)
    const int ksw = ((lane >> 4) ^ ((q15 >> 1) & 3)) * 8;   // swizzled read chunk (u16)

    const u16* gA0 = A + (size_t)(m0 + wave * 16 + lrow) * ldK + csw;
    const u16* gA1 = gA0 + (size_t)128 * ldK;
    const u16* gB0 = Bt + (size_t)(n0 + wave * 16 + lrow) * ldK + csw;
    const u16* gB1 = gB0 + (size_t)128 * ldK;

#pragma unroll
    for (int i = 0; i < 8; ++i)
#pragma unroll
        for (int j = 0; j < 4; ++j) acc[i][j] = (f32x4){0.f, 0.f, 0.f, 0.f};

    // ---- prologue: tile 0 fully + tile 1 A-halves ----
    STG(sA, gA0, 0, 0); STG(sA, gA1, 128, 0);
    STG(sB, gB0, 0, 0); STG(sB, gB1, 128, 0);
    if (NT > 1) {
        STG(sA, gA0, 0, 1); STG(sA, gA1, 128, 1);
        VMW(4);
    } else {
        VMW(0);
    }
    BARR();

    bf16x8 af0[4][2], af1[4][2], bf[2][2];

    for (int t = 0; t < NT; ++t) {
        const int buf = t & 1;
        // ---- phase 1: A rows [wm,wm+64) + B cols [wn,wn+32) ; stage B0(t+1)
        LD_A(af0, wm128);
        LD_B(0);
        if (t + 1 < NT) STG(sB, gB0, 0, t + 1);
        BARR();
        MFMA_PH(af0, 0, 0);
        BARR();
        // ---- phase 2: A rows [wm+64,wm+128) ; stage B1(t+1)
        LD_A(af1, wm128 + 64);
        if (t + 1 < NT) STG(sB, gB1, 128, t + 1);
        BARR();
        MFMA_PH(af1, 4, 0);
        BARR();
        // ---- phase 3: B cols [wn+32,wn+64) ; stage A0(t+2)
        LD_B(32);
        if (t + 2 < NT) STG(sA, gA0, 0, t + 2);
        BARR();
        MFMA_PH(af0, 0, 2);
        BARR();
        // ---- phase 4: stage A1(t+2) ; counted vmcnt at the tile boundary
        if (t + 2 < NT) {
            STG(sA, gA1, 128, t + 2);
            VMW(4);
        } else {
            VMW(0);
        }
        BARR();
        MFMA_PH(af1, 4, 2);
        BARR();
    }
}

// ---------------------------------------------------------------------------
// FFN1 on the 8-phase core: C = relu(A @ Bt^T + bias). M=4096, N=4096,
// K=1024. grid (16, 16) = 256 blocks exactly -> single round. 512 threads.
// ---------------------------------------------------------------------------
__global__ __launch_bounds__(512) void gemm8p_ffn1(
    const u16* __restrict__ A, const u16* __restrict__ Bt,
    const u16* __restrict__ bias, u16* __restrict__ C, int N, int NT)
{
    const int m0 = blockIdx.y * 256;
    const int n0 = blockIdx.x * 256;

    f32x4 acc[8][4];
    gemm8p_core(A, Bt, 1024, NT, m0, n0, acc);

    const int tid = threadIdx.x;
    const int wave = tid >> 6, lane = tid & 63;
    const int q15 = lane & 15;
    const int wm128 = (wave >> 2) * 128;
    const int wn64 = (wave & 3) * 64;
    const int rq = (lane >> 4) * 4;

#pragma unroll
    for (int nf = 0; nf < 4; ++nf) {
        const int col = n0 + wn64 + nf * 16 + q15;
        const float bv = b2f(bias[col]);
#pragma unroll
        for (int mf = 0; mf < 8; ++mf) {
            const int row = m0 + wm128 + mf * 16 + rq;
            f32x4 v = acc[mf][nf];
#pragma unroll
            for (int e = 0; e < 4; ++e)
                C[(size_t)(row + e) * N + col] = f2b(fmaxf(v[e] + bv, 0.f));
        }
    }
}

// ---------------------------------------------------------------------------
// FFN2 on the 8-phase core, split-K=3 (22/21/21 K-tiles), fp32 partials.
// M=4096, N=1024, K=4096. grid (4, 16, 3) = 192 blocks -> single round.
// z==0 adds bias.
// ---------------------------------------------------------------------------
__global__ __launch_bounds__(512) void gemm8p_ffn2(
    const u16* __restrict__ A, const u16* __restrict__ Bt,
    const u16* __restrict__ bias,
    float* __restrict__ P0, float* __restrict__ P1, float* __restrict__ P2)
{
    const int z = blockIdx.z;
    const int t0 = (z == 0) ? 0 : (22 + 21 * (z - 1));
    const int nt = (z == 0) ? 22 : 21;
    const int m0 = blockIdx.y * 256;
    const int n0 = blockIdx.x * 256;

    f32x4 acc[8][4];
    gemm8p_core(A + t0 * 64, Bt + t0 * 64, 4096, nt, m0, n0, acc);

    const int tid = threadIdx.x;
    const int wave = tid >> 6, lane = tid & 63;
    const int q15 = lane & 15;
    const int wm128 = (wave >> 2) * 128;
    const int wn64 = (wave & 3) * 64;
    const int rq = (lane >> 4) * 4;

    float* P = (z == 0) ? P0 : (z == 1) ? P1 : P2;
#pragma unroll
    for (int nf = 0; nf < 4; ++nf) {
        const int col = n0 + wn64 + nf * 16 + q15;
        const float bv = (z == 0) ? b2f(bias[col]) : 0.f;
#pragma unroll
        for (int mf = 0; mf < 8; ++mf) {
            const int row = m0 + wm128 + mf * 16 + rq;
            f32x4 v = acc[mf][nf];
#pragma unroll
            for (int e = 0; e < 4; ++e)
                P[(size_t)(row + e) * 1024 + col] = v[e] + bv;
        }
    }
}

// ---------------------------------------------------------------------------
// GEMM 64x128 tile, BK=64 panelized, global_load_lds staging (R8-verified).
// N=1024 shapes (K=1024). grid (M/64, 8). flags: 1=relu, 4=scale by QSCALE.
// ---------------------------------------------------------------------------
__global__ __launch_bounds__(256) void gemm_n1k(
    const u16* __restrict__ A, const u16* __restrict__ Bt,
    const u16* __restrict__ bias, const u16* __restrict__ resid,
    u16* __restrict__ C, int M, int N, int K, int flags)
{
    __shared__ u16 sA[2][64 * 32];
    __shared__ u16 sB[2][128 * 32];
    const int tid = threadIdx.x;
    const int wave = tid >> 6;
    const int lane = tid & 63;
    const int m0 = blockIdx.x * 64;
    const int n0 = blockIdx.y * 128;
    const int wm = (wave >> 1) * 32;
    const int wn = (wave & 1) * 64;

    const int lrow = lane >> 2;
    const int lcol = (lane & 3) * 8;
    const u16* gA = A + (size_t)(m0 + wave * 16 + lrow) * K + lcol;
    const u16* gB = Bt + (size_t)(n0 + wave * 32 + lrow) * K + lcol;
    const u16* gB2 = gB + (size_t)16 * K;
    const int lofsA = wave * 16 * 32;
    const int lofsB = wave * 32 * 32;

    f32x4 acc[2][4];
#pragma unroll
    for (int i = 0; i < 2; ++i)
#pragma unroll
        for (int j = 0; j < 4; ++j) acc[i][j] = (f32x4){0.f, 0.f, 0.f, 0.f};

    const int q15 = lane & 15;
    const int koff = (lane >> 4) * 8;

    for (int k0 = 0; k0 < K; k0 += 64) {
        __syncthreads();
        gload_lds16(gA + k0,      &sA[0][lofsA]);
        gload_lds16(gA + k0 + 32, &sA[1][lofsA]);
        gload_lds16(gB + k0,       &sB[0][lofsB]);
        gload_lds16(gB + k0 + 32,  &sB[1][lofsB]);
        gload_lds16(gB2 + k0,      &sB[0][lofsB + 16 * 32]);
        gload_lds16(gB2 + k0 + 32, &sB[1][lofsB + 16 * 32]);
        __syncthreads();
#pragma unroll 1
        for (int p = 0; p < 2; ++p) {
            bf16x8 af[2], bfr[4];
#pragma unroll
            for (int mt = 0; mt < 2; ++mt)
                af[mt] = *(const bf16x8*)(&sA[p][(wm + mt * 16 + q15) * 32 + koff]);
#pragma unroll
            for (int nt = 0; nt < 4; ++nt)
                bfr[nt] = *(const bf16x8*)(&sB[p][(wn + nt * 16 + q15) * 32 + koff]);
#pragma unroll
            for (int mt = 0; mt < 2; ++mt)
#pragma unroll
                for (int nt = 0; nt < 4; ++nt)
                    acc[mt][nt] = MFMA16(af[mt], bfr[nt], acc[mt][nt]);
        }
    }

    const int rq = (lane >> 4) * 4;
#pragma unroll
    for (int nt = 0; nt < 4; ++nt) {
        const int col = n0 + wn + nt * 16 + q15;
        const float bv = b2f(bias[col]);
#pragma unroll
        for (int mt = 0; mt < 2; ++mt) {
            const int row = m0 + wm + mt * 16 + rq;
            f32x4 v = acc[mt][nt];
#pragma unroll
            for (int e = 0; e < 4; ++e) {
                float val = v[e] + bv;
                if (flags & 1) val = fmaxf(val, 0.f);
                if (flags & 4) val *= QSCALE;
                const size_t o = (size_t)(row + e) * N + col;
                if (resid) val += b2f(resid[o]);
                C[o] = f2b(val);
            }
        }
    }
}

// ---------------------------------------------------------------------------
// Flash attention (no mask). Q,K: [B*S, H*R]; Vt: [B,H,R,S]; O: [B*S, H*R].
// grid 1024, flat id = qt*64 + (b*16+h). Rows padded to 72 (2-way aliasing).
// Q is pre-scaled by QSCALE at projection time, so P = exp2(QK) directly.
// R6: T5 s_setprio(1) around the QK^T and PV MFMA clusters (m191: attn
// blocks are independent, multi-block/CU -> scheduler has waves to demote).
// ---------------------------------------------------------------------------
__global__ __launch_bounds__(256) void attn_k(
    const u16* __restrict__ Q, const u16* __restrict__ K,
    const u16* __restrict__ Vt, u16* __restrict__ O)
{
    __shared__ u16 sK[64 * 72];
    __shared__ u16 sV[64 * 72];
    __shared__ u16 sP[4][16 * 72];
    const int tid = threadIdx.x, wave = tid >> 6, lane = tid & 63;
    const int q15 = lane & 15, quad = lane >> 4;
    const int bid = blockIdx.x;
    const int g = bid & 63, qt = bid >> 6;
    const int h = g & 15, b = g >> 4;

    const u16* qb = Q + ((size_t)(b * 1024 + qt * 64 + wave * 16 + q15)) * 1024 + h * 64 + quad * 8;
    const bf16x8 qa0 = *(const bf16x8*)qb;
    const bf16x8 qa1 = *(const bf16x8*)(qb + 32);

    bf16x8 vone;
#pragma unroll
    for (int i = 0; i < 8; ++i) vone[i] = (__bf16)1.0f;

    f32x4 oacc[4];
#pragma unroll
    for (int i = 0; i < 4; ++i) oacc[i] = (f32x4){0.f, 0.f, 0.f, 0.f};
    f32x4 lacc = (f32x4){0.f, 0.f, 0.f, 0.f};

    const int srow = lane >> 3, scol8 = (lane & 7) * 8;
    const u16* kg = K + ((size_t)(b * 1024 + wave * 8 + srow)) * 1024 + h * 64 + scol8;
    const u16* vg = Vt + ((size_t)((b * 16 + h) * 64 + wave * 8 + srow)) * 1024 + scol8;
    u16* lKw = sK + (wave * 8 + srow) * 72 + scol8;
    u16* lVw = sV + (wave * 8 + srow) * 72 + scol8;

    uint4 k0r = *(const uint4*)kg;
    uint4 k1r = *(const uint4*)(kg + (size_t)32 * 1024);
    uint4 v0r = *(const uint4*)vg;
    uint4 v1r = *(const uint4*)(vg + (size_t)32 * 1024);

    for (int tt = 0; tt < 16; ++tt) {
        __syncthreads();
        *(uint4*)lKw = k0r;
        *(uint4*)(lKw + 32 * 72) = k1r;
        *(uint4*)lVw = v0r;
        *(uint4*)(lVw + 32 * 72) = v1r;
        __syncthreads();
        if (tt < 15) {
            const size_t t1 = (size_t)(tt + 1) * 64;
            k0r = *(const uint4*)(kg + t1 * 1024);
            k1r = *(const uint4*)(kg + t1 * 1024 + (size_t)32 * 1024);
            v0r = *(const uint4*)(vg + t1);
            v1r = *(const uint4*)(vg + t1 + (size_t)32 * 1024);
        }

        f32x4 sc[4];
        __builtin_amdgcn_s_setprio(1);
#pragma unroll
        for (int nf = 0; nf < 4; ++nf) {
            bf16x8 kb0 = *(const bf16x8*)(sK + (nf * 16 + q15) * 72 + quad * 8);
            bf16x8 kb1 = *(const bf16x8*)(sK + (nf * 16 + q15) * 72 + 32 + quad * 8);
            f32x4 t = (f32x4){0.f, 0.f, 0.f, 0.f};
            t = MFMA16(qa0, kb0, t);
            t = MFMA16(qa1, kb1, t);
            sc[nf] = t;
        }
        __builtin_amdgcn_s_setprio(0);
#pragma unroll
        for (int nf = 0; nf < 4; ++nf)
#pragma unroll
            for (int e = 0; e < 4; ++e) sc[nf][e] = fexp2(sc[nf][e]);
#pragma unroll
        for (int nf = 0; nf < 4; ++nf)
#pragma unroll
            for (int e = 0; e < 4; ++e)
                sP[wave][(quad * 4 + e) * 72 + nf * 16 + q15] = f2b(sc[nf][e]);
        asm volatile("s_waitcnt lgkmcnt(0)" ::: "memory");
        const bf16x8 pa0 = *(const bf16x8*)(sP[wave] + q15 * 72 + quad * 8);
        const bf16x8 pa1 = *(const bf16x8*)(sP[wave] + q15 * 72 + 32 + quad * 8);
        __builtin_amdgcn_s_setprio(1);
#pragma unroll
        for (int rf = 0; rf < 4; ++rf) {
            bf16x8 vb0 = *(const bf16x8*)(sV + (rf * 16 + q15) * 72 + quad * 8);
            bf16x8 vb1 = *(const bf16x8*)(sV + (rf * 16 + q15) * 72 + 32 + quad * 8);
            oacc[rf] = MFMA16(pa0, vb0, oacc[rf]);
            oacc[rf] = MFMA16(pa1, vb1, oacc[rf]);
        }
        lacc = MFMA16(pa0, vone, lacc);
        lacc = MFMA16(pa1, vone, lacc);
        __builtin_amdgcn_s_setprio(0);
    }
#pragma unroll
    for (int rf = 0; rf < 4; ++rf)
#pragma unroll
        for (int e = 0; e < 4; ++e) {
            const float v = oacc[rf][e] / lacc[e];
            const size_t row = (size_t)(b * 1024 + qt * 64 + wave * 16 + quad * 4 + e);
            O[row * 1024 + h * 64 + rf * 16 + q15] = f2b(v);
        }
}

// ---------------------------------------------------------------------------
// LayerNorm over last dim (1024), eps=1e-3. One wave/row, 4 rows/block.
// ---------------------------------------------------------------------------
__global__ __launch_bounds__(256) void ln_k(
    const u16* __restrict__ y, const u16* __restrict__ g,
    const u16* __restrict__ be, void* __restrict__ out, const int* __restrict__ oflag)
{
    const int f = oflag ? *oflag : 0;
    const int tid = threadIdx.x, wave = tid >> 6, lane = tid & 63;
    const size_t row = (size_t)blockIdx.x * 4 + wave;
    const u16* p = y + row * 1024 + lane * 16;
    uint4 u0 = *(const uint4*)p;
    uint4 u1 = *(const uint4*)(p + 8);
    float v[16];
    unpack8(u0, v);
    unpack8(u1, v + 8);
    float s = 0.f, s2 = 0.f;
#pragma unroll
    for (int i = 0; i < 16; ++i) { s += v[i]; s2 += v[i] * v[i]; }
#pragma unroll
    for (int off = 1; off < 64; off <<= 1) {
        s += __shfl_xor(s, off, 64);
        s2 += __shfl_xor(s2, off, 64);
    }
    const float mean = s * (1.f / 1024.f);
    const float var = s2 * (1.f / 1024.f) - mean * mean;
    const float rstd = rsqrtf(var + 1e-3f);
    uint4 g0 = *(const uint4*)(g + lane * 16);
    uint4 g1 = *(const uint4*)(g + lane * 16 + 8);
    uint4 b0 = *(const uint4*)(be + lane * 16);
    uint4 b1 = *(const uint4*)(be + lane * 16 + 8);
    float gv[16], bv[16];
    unpack8(g0, gv); unpack8(g1, gv + 8);
    unpack8(b0, bv); unpack8(b1, bv + 8);
    float w[16];
#pragma unroll
    for (int i = 0; i < 16; ++i) w[i] = (v[i] - mean) * rstd * gv[i] + bv[i];
    if (f) {
        float* q = (float*)out + row * 1024 + lane * 16;
#pragma unroll
        for (int i = 0; i < 16; i += 4)
            *(float4*)(q + i) = make_float4(w[i], w[i + 1], w[i + 2], w[i + 3]);
    } else {
        uint4 o0, o1;
        o0.x = pack2(w[0], w[1]);   o0.y = pack2(w[2], w[3]);
        o0.z = pack2(w[4], w[5]);   o0.w = pack2(w[6], w[7]);
        o1.x = pack2(w[8], w[9]);   o1.y = pack2(w[10], w[11]);
        o1.z = pack2(w[12], w[13]); o1.w = pack2(w[14], w[15]);
        u16* q = (u16*)out + row * 1024 + lane * 16;
        *(uint4*)q = o0;
        *(uint4*)(q + 8) = o1;
    }
}

// ---------------------------------------------------------------------------
// Fused split-K reduce (3 partials) + residual + LayerNorm -> d_out.
// ---------------------------------------------------------------------------
__global__ __launch_bounds__(256) void ln3f_k(
    const float* __restrict__ p0, const float* __restrict__ p1,
    const float* __restrict__ p2,
    const u16* __restrict__ resid, const u16* __restrict__ g,
    const u16* __restrict__ be, void* __restrict__ out, const int* __restrict__ oflag)
{
    const int f = *oflag;
    const int tid = threadIdx.x, wave = tid >> 6, lane = tid & 63;
    const size_t row = (size_t)blockIdx.x * 4 + wave;
    const size_t base = row * 1024 + lane * 16;
    float v[16];
#pragma unroll
    for (int i = 0; i < 16; i += 4) {
        float4 a = *(const float4*)(p0 + base + i);
        float4 b = *(const float4*)(p1 + base + i);
        float4 c = *(const float4*)(p2 + base + i);
        v[i + 0] = a.x + b.x + c.x; v[i + 1] = a.y + b.y + c.y;
        v[i + 2] = a.z + b.z + c.z; v[i + 3] = a.w + b.w + c.w;
    }
    uint4 r0 = *(const uint4*)(resid + base);
    uint4 r1 = *(const uint4*)(resid + base + 8);
    float rv[16];
    unpack8(r0, rv); unpack8(r1, rv + 8);
#pragma unroll
    for (int i = 0; i < 16; ++i) v[i] += rv[i];
    float s = 0.f, s2 = 0.f;
#pragma unroll
    for (int i = 0; i < 16; ++i) { s += v[i]; s2 += v[i] * v[i]; }
#pragma unroll
    for (int off = 1; off < 64; off <<= 1) {
        s += __shfl_xor(s, off, 64);
        s2 += __shfl_xor(s2, off, 64);
    }
    const float mean = s * (1.f / 1024.f);
    const float var = s2 * (1.f / 1024.f) - mean * mean;
    const float rstd = rsqrtf(var + 1e-3f);
    uint4 g0 = *(const uint4*)(g + lane * 16);
    uint4 g1 = *(const uint4*)(g + lane * 16 + 8);
    uint4 b0 = *(const uint4*)(be + lane * 16);
    uint4 b1 = *(const uint4*)(be + lane * 16 + 8);
    float gv[16], bv[16];
    unpack8(g0, gv); unpack8(g1, gv + 8);
    unpack8(b0, bv); unpack8(b1, bv + 8);
    float w[16];
#pragma unroll
    for (int i = 0; i < 16; ++i) w[i] = (v[i] - mean) * rstd * gv[i] + bv[i];
    if (f) {
        float* q = (float*)out + base;
#pragma unroll
        for (int i = 0; i < 16; i += 4)
            *(float4*)(q + i) = make_float4(w[i], w[i + 1], w[i + 2], w[i + 3]);
    } else {
        uint4 o0, o1;
        o0.x = pack2(w[0], w[1]);   o0.y = pack2(w[2], w[3]);
        o0.z = pack2(w[4], w[5]);   o0.w = pack2(w[6], w[7]);
        o1.x = pack2(w[8], w[9]);   o1.y = pack2(w[10], w[11]);
        o1.z = pack2(w[12], w[13]); o1.w = pack2(w[14], w[15]);
        u16* q = (u16*)out + base;
        *(uint4*)q = o0;
        *(uint4*)(q + 8) = o1;
    }
}

// ---------------------------------------------------------------------------
extern "C" void kernel_launch(void* const* d_in, const int* in_sizes, int n_in,
                              void* d_out, int out_size, void* d_ws, size_t ws_size,
                              hipStream_t stream)
{
    (void)in_sizes; (void)n_in; (void)out_size; (void)ws_size;
    const void* x   = d_in[0];
    const void* ctx = d_in[1];

    u16* ws = (u16*)d_ws;
    const size_t MEG = 1u << 20;
    u16* wT      = ws;               // 0..16M elems: transposed weights
    u16* bufx    = ws + 16 * MEG;
    u16* bufctx  = ws + 20 * MEG;
    u16* bufq    = ws + 24 * MEG;
    u16* bufk_sa = ws + 28 * MEG;
    u16* bufvt_sa= ws + 32 * MEG;
    u16* bufk_ca = ws + 36 * MEG;
    u16* bufvt_ca= ws + 40 * MEG;
    u16* bufo    = ws + 44 * MEG;
    u16* bufln   = ws + 48 * MEG;
    u16* small   = ws + 52 * MEG;
    int* flag    = (int*)(small + 20480);
    u16* bufh    = ws + 16 * MEG;    // FFN hidden (16..32M; bufx/ctx/q/k_sa dead)
    // split-K=3 fp32 partials (each 4096x1024 f32 = 16 MB = 8M u16):
    //  p0: 32..40M (bufvt_sa dead), p1: 40..48M (bufvt_ca/bufo dead),
    //  p2: 4..12M (wT[4..12M] all consumed before FFN2; wT[12..16M] stays live)
    float* part0 = (float*)(ws + 32 * MEG);
    float* part1 = (float*)(ws + 40 * MEG);
    float* part2 = (float*)(ws + 4 * MEG);

    const int O_SABQ = 0,    O_SABK = 1024, O_SABV = 2048;
    const int O_CABK = 3072, O_CABV = 4096, O_CABQ = 5120;
    const int O_SABO = 6144, O_CABO = 7168;
    const int O_L1G = 8192,  O_L1B = 9216,  O_L2G = 10240, O_L2B = 11264;
    const int O_L3G = 12288, O_L3B = 13312, O_FB1 = 14336, O_FB2 = 18432;

    PtrTab tab;
    const void* sp[16] = { d_in[3], d_in[5], d_in[7], d_in[13], d_in[15], d_in[11],
                           d_in[9], d_in[17],
                           d_in[18], d_in[19], d_in[20], d_in[21], d_in[22], d_in[23],
                           d_in[25], d_in[27] };
    const int so[16] = { O_SABQ, O_SABK, O_SABV, O_CABK, O_CABV, O_CABQ, O_SABO, O_CABO,
                         O_L1G, O_L1B, O_L2G, O_L2B, O_L3G, O_L3B, O_FB1, O_FB2 };
    const int sc[16] = { 1024, 1024, 1024, 1024, 1024, 1024, 1024, 1024,
                         1024, 1024, 1024, 1024, 1024, 1024, 4096, 1024 };
    for (int i = 0; i < 16; ++i) { tab.p[i] = sp[i]; tab.off[i] = so[i]; tab.cnt[i] = sc[i]; }

    PtrTab tab6;
    const void* wp[6] = { d_in[2], d_in[4], d_in[6], d_in[12], d_in[14], d_in[10] };
    for (int i = 0; i < 6; ++i) tab6.p[i] = wp[i];

    const dim3 blk(256);
    const dim3 blk8(512);
    const dim3 gN1(64, 8);

    // ---- dtype normalize + weight prep (R6-verified chain) ----
    detect_k<<<1, blk, 0, stream>>>((const u32*)x, flag);
    conv2_k<<<dim3(2048, 2), blk, 0, stream>>>(x, ctx, bufx, bufctx, 4 * MEG, flag);
    conv_small_k<<<dim3(16), blk, 0, stream>>>(tab, small, flag);
    transpose6_k<<<dim3(1, 16, 96), blk, 0, stream>>>(tab6, wT, flag);
    transpose_k<<<dim3(16, 16), blk, 0, stream>>>(d_in[8],  wT + 6 * MEG, 1024, 1024, flag);
    transpose_k<<<dim3(16, 16), blk, 0, stream>>>(d_in[16], wT + 7 * MEG, 1024, 1024, flag);
    transpose_k<<<dim3(64, 16), blk, 0, stream>>>(d_in[24], wT + 8 * MEG, 1024, 4096, flag);
    transpose_k<<<dim3(16, 64), blk, 0, stream>>>(d_in[26], wT + 12 * MEG, 4096, 1024, flag);

    // ---- fused projections (SA-Q pre-scaled by QSCALE) ----
    gemm_qkv_k<<<dim3(40, 32), blk, 0, stream>>>(bufx, bufctx, wT, small,
                                                 bufq, bufk_sa, bufvt_sa, bufk_ca, bufvt_ca);

    // ---- self-attention ----
    attn_k<<<dim3(1024), blk, 0, stream>>>(bufq, bufk_sa, bufvt_sa, bufo);
    gemm_n1k<<<gN1, blk, 0, stream>>>(bufo, wT + 6 * MEG, small + O_SABO, bufx,
                                      bufq, 4096, 1024, 1024, 0);
    ln_k<<<dim3(1024), blk, 0, stream>>>(bufq, small + O_L1G, small + O_L1B, bufln, nullptr);

    // ---- cross-attention (CA-Q pre-scaled via flags|4) ----
    gemm_n1k<<<gN1, blk, 0, stream>>>(bufln, wT + 5 * MEG, small + O_CABQ, nullptr,
                                      bufq, 4096, 1024, 1024, 4);
    attn_k<<<dim3(1024), blk, 0, stream>>>(bufq, bufk_ca, bufvt_ca, bufo);
    gemm_n1k<<<gN1, blk, 0, stream>>>(bufo, wT + 7 * MEG, small + O_CABO, bufln,
                                      bufq, 4096, 1024, 1024, 0);
    ln_k<<<dim3(1024), blk, 0, stream>>>(bufq, small + O_L2G, small + O_L2B, bufln, nullptr);

    // ---- FFN (256^2 8-phase; FFN2 split-K=3 + fused reduce/LN) ----
    gemm8p_ffn1<<<dim3(16, 16), blk8, 0, stream>>>(bufln, wT + 8 * MEG, small + O_FB1,
                                                   bufh, 4096, 16);
    gemm8p_ffn2<<<dim3(4, 16, 3), blk8, 0, stream>>>(bufh, wT + 12 * MEG, small + O_FB2,
                                                     part0, part1, part2);
    ln3f_k<<<dim3(1024), blk, 0, stream>>>(part0, part1, part2, bufln,
                                           small + O_L3G, small + O_L3B, d_out, flag);
}

// Round 7
// 515.838 us; speedup vs baseline: 1.0141x; 1.0088x over previous
//
#include <hip/hip_runtime.h>
#include <math.h>

typedef unsigned short u16;
typedef unsigned int u32;
typedef __bf16 bf16x8 __attribute__((ext_vector_type(8)));
typedef float f32x4 __attribute__((ext_vector_type(4)));

#define MFMA16(a, b, c) __builtin_amdgcn_mfma_f32_16x16x32_bf16(a, b, c, 0, 0, 0)

// QSCALE = (1/sqrt(64)) * log2(e): folded into Q at projection time so the
// attention inner loop needs only v_exp_f32 (2^x).
#define QSCALE 0.1803368801111204f

typedef __attribute__((address_space(1))) void gvoid;
typedef __attribute__((address_space(3))) void lvoid;

__device__ __forceinline__ void gload_lds16(const void* g, void* l) {
    __builtin_amdgcn_global_load_lds((gvoid*)g, (lvoid*)l, 16, 0, 0);
}

__device__ __forceinline__ float fexp2(float x) {
#if __has_builtin(__builtin_amdgcn_exp2f)
    return __builtin_amdgcn_exp2f(x);
#else
    return __expf(x * 0.6931471805599453f);
#endif
}

__device__ __forceinline__ float b2f(u16 u) {
    union { u32 i; float f; } w;
    w.i = ((u32)u) << 16;
    return w.f;
}

__device__ __forceinline__ u16 f2b(float f) {
    union { float f; u32 i; } w;
    w.f = f;
    u32 x = w.i;
    u32 r = (x + 0x7fffu + ((x >> 16) & 1u)) >> 16;  // RNE
    return (u16)r;
}

__device__ __forceinline__ void unpack8(uint4 u, float* v) {
    v[0] = b2f((u16)(u.x & 0xffff)); v[1] = b2f((u16)(u.x >> 16));
    v[2] = b2f((u16)(u.y & 0xffff)); v[3] = b2f((u16)(u.y >> 16));
    v[4] = b2f((u16)(u.z & 0xffff)); v[5] = b2f((u16)(u.z >> 16));
    v[6] = b2f((u16)(u.w & 0xffff)); v[7] = b2f((u16)(u.w >> 16));
}

__device__ __forceinline__ u32 pack2(float a, float b) {
    return (u32)f2b(a) | ((u32)f2b(b) << 16);
}

// ---------------------------------------------------------------------------
// Input dtype detector: flag=1 -> fp32 inputs.
// ---------------------------------------------------------------------------
__global__ __launch_bounds__(256) void detect_k(const u32* __restrict__ x, int* __restrict__ flag)
{
    __shared__ int cnt[256];
    int c = 0;
#pragma unroll 4
    for (int i = 0; i < 256; ++i) {
        const u32 w = x[threadIdx.x * 256 + i];
        const u32 e = (w >> 7) & 0xFF;
        c += (e < 0x20 || e > 0x4F) ? 1 : 0;
    }
    cnt[threadIdx.x] = c;
    __syncthreads();
    if (threadIdx.x == 0) {
        int t = 0;
        for (int i = 0; i < 256; ++i) t += cnt[i];
        *flag = (t > 16384) ? 1 : 0;
    }
}

// Convert x and context in one dispatch: blockIdx.y selects tensor.
__global__ __launch_bounds__(256) void conv2_k(
    const void* __restrict__ a, const void* __restrict__ b,
    u16* __restrict__ oa, u16* __restrict__ ob, int n, const int* __restrict__ flag)
{
    const int f = *flag;
    const void* in = blockIdx.y ? b : a;
    u16* out = blockIdx.y ? ob : oa;
    const int i = (blockIdx.x * 256 + threadIdx.x) * 8;
    if (i >= n) return;
    if (f) {
        const float* p = (const float*)in + i;
        uint4 o;
        o.x = pack2(p[0], p[1]); o.y = pack2(p[2], p[3]);
        o.z = pack2(p[4], p[5]); o.w = pack2(p[6], p[7]);
        *(uint4*)(out + i) = o;
    } else {
        *(uint4*)(out + i) = *(const uint4*)((const u16*)in + i);
    }
}

struct PtrTab {
    const void* p[16];
    int off[16];
    int cnt[16];
};

__global__ __launch_bounds__(256) void conv_small_k(
    PtrTab t, u16* __restrict__ out, const int* __restrict__ flag)
{
    const int f = *flag;
    const void* src = t.p[blockIdx.x];
    const int n = t.cnt[blockIdx.x];
    u16* dst = out + t.off[blockIdx.x];
    for (int i = threadIdx.x; i < n; i += 256)
        dst[i] = f ? f2b(((const float*)src)[i]) : ((const u16*)src)[i];
}

// ---------------------------------------------------------------------------
// Generic transpose: in [rows][cols] -> out bf16 [cols][rows].
// ---------------------------------------------------------------------------
__global__ __launch_bounds__(256) void transpose_k(
    const void* __restrict__ in, u16* __restrict__ out, int rows, int cols,
    const int* __restrict__ flag)
{
    const int f = *flag;
    __shared__ u16 t[64][65];
    const int tid = threadIdx.x;
    const int lr = tid >> 4;
    const int lc = (tid & 15) * 4;
    const int r0 = blockIdx.y * 64, c0 = blockIdx.x * 64;
#pragma unroll
    for (int i = 0; i < 4; ++i) {
        const size_t off = (size_t)(r0 + i * 16 + lr) * cols + c0 + lc;
        if (f) {
            const float* p = (const float*)in + off;
            t[i * 16 + lr][lc + 0] = f2b(p[0]);
            t[i * 16 + lr][lc + 1] = f2b(p[1]);
            t[i * 16 + lr][lc + 2] = f2b(p[2]);
            t[i * 16 + lr][lc + 3] = f2b(p[3]);
        } else {
            const u16* p = (const u16*)in + off;
            t[i * 16 + lr][lc + 0] = p[0];
            t[i * 16 + lr][lc + 1] = p[1];
            t[i * 16 + lr][lc + 2] = p[2];
            t[i * 16 + lr][lc + 3] = p[3];
        }
    }
    __syncthreads();
#pragma unroll
    for (int i = 0; i < 4; ++i) {
        const int rr = i * 16 + lr;
        uint2 o;
        o.x = (u32)t[lc + 0][rr] | ((u32)t[lc + 1][rr] << 16);
        o.y = (u32)t[lc + 2][rr] | ((u32)t[lc + 3][rr] << 16);
        *(uint2*)(out + (size_t)(c0 + rr) * rows + r0 + lc) = o;
    }
}

// ---------------------------------------------------------------------------
// Fused transpose of the 6 head-blocked weights [16,1024,64] -> [1024,1024].
// grid (1, 16, 96): z = w*16 + h.
// ---------------------------------------------------------------------------
__global__ __launch_bounds__(256) void transpose6_k(
    PtrTab tab, u16* __restrict__ wT, const int* __restrict__ flag)
{
    const int f = *flag;
    __shared__ u16 t[64][65];
    const int tid = threadIdx.x;
    const int lr = tid >> 4;
    const int lc = (tid & 15) * 4;
    const int w = blockIdx.z >> 4, h = blockIdx.z & 15;
    const void* in = tab.p[w];
    u16* out = wT + (size_t)w * (1u << 20) + h * 65536;
    const size_t ibase = (size_t)h * 65536;
    const int r0 = blockIdx.y * 64;
#pragma unroll
    for (int i = 0; i < 4; ++i) {
        const size_t off = ibase + (size_t)(r0 + i * 16 + lr) * 64 + lc;
        if (f) {
            const float* p = (const float*)in + off;
            t[i * 16 + lr][lc + 0] = f2b(p[0]);
            t[i * 16 + lr][lc + 1] = f2b(p[1]);
            t[i * 16 + lr][lc + 2] = f2b(p[2]);
            t[i * 16 + lr][lc + 3] = f2b(p[3]);
        } else {
            const u16* p = (const u16*)in + off;
            t[i * 16 + lr][lc + 0] = p[0];
            t[i * 16 + lr][lc + 1] = p[1];
            t[i * 16 + lr][lc + 2] = p[2];
            t[i * 16 + lr][lc + 3] = p[3];
        }
    }
    __syncthreads();
#pragma unroll
    for (int i = 0; i < 4; ++i) {
        const int rr = i * 16 + lr;
        uint2 o;
        o.x = (u32)t[lc + 0][rr] | ((u32)t[lc + 1][rr] << 16);
        o.y = (u32)t[lc + 2][rr] | ((u32)t[lc + 3][rr] << 16);
        *(uint2*)(out + (size_t)rr * 1024 + r0 + lc) = o;
    }
}

// ---------------------------------------------------------------------------
// Grouped projection GEMM, BK=64 panelized, register-prefetch staging.
// M=4096, K=1024. grid (40, 32). SA-Q output pre-scaled by QSCALE (fp32).
// R5/R6 verdicts: LDS chunk XOR-swizzle KEPT (conflicts 5.24M->0);
// XCD remap refuted+reverted (FETCH 81->90.5MB). Near structure ceiling.
// ---------------------------------------------------------------------------
__global__ __launch_bounds__(256) void gemm_qkv_k(
    const u16* __restrict__ X, const u16* __restrict__ CTX,
    const u16* __restrict__ wT, const u16* __restrict__ bias,
    u16* __restrict__ Qo, u16* __restrict__ Ksa, u16* __restrict__ Vsa,
    u16* __restrict__ Kca, u16* __restrict__ Vca)
{
    __shared__ u16 sA[2][128 * 32];
    __shared__ u16 sB[2][128 * 32];
    const int tid = threadIdx.x;
    const int wave = tid >> 6;
    const int lane = tid & 63;

    const int bx = blockIdx.x;
    const int by = blockIdx.y;

    const int seg = bx >> 3, c8 = bx & 7;
    const int m0 = by * 128;
    const int wm = (wave >> 1) * 64;
    const int wn = (wave & 1) * 64;
    const u16* A = (seg < 3) ? X : CTX;

    const int lrow = lane >> 2;
    const int lcol = (lane & 3) * 8;
    const u16* gA = A + (size_t)(m0 + wave * 16 + lrow) * 1024 + lcol;
    const u16* gB = wT + (size_t)(bx * 128 + wave * 16 + lrow) * 1024 + lcol;
    const int lofs = wave * 16 * 32;
    // swizzled write chunk: row within buffer = wave*16+lrow; key=(row>>1)&3
    // == (lrow>>1)&3 since wave*16>>1 is 0 mod 4.
    const int wsw = lofs + lrow * 32 + (((lane & 3) ^ ((lrow >> 1) & 3)) * 8);

    u16* dA0 = &sA[0][wsw];
    u16* dA1 = &sA[1][wsw];
    u16* dA2 = &sA[0][64 * 32 + wsw];
    u16* dA3 = &sA[1][64 * 32 + wsw];
    u16* dB0 = &sB[0][wsw];
    u16* dB1 = &sB[1][wsw];
    u16* dB2 = &sB[0][64 * 32 + wsw];
    u16* dB3 = &sB[1][64 * 32 + wsw];

    uint4 rA0 = *(const uint4*)(gA);
    uint4 rA1 = *(const uint4*)(gA + 32);
    uint4 rA2 = *(const uint4*)(gA + (size_t)64 * 1024);
    uint4 rA3 = *(const uint4*)(gA + (size_t)64 * 1024 + 32);
    uint4 rB0 = *(const uint4*)(gB);
    uint4 rB1 = *(const uint4*)(gB + 32);
    uint4 rB2 = *(const uint4*)(gB + (size_t)64 * 1024);
    uint4 rB3 = *(const uint4*)(gB + (size_t)64 * 1024 + 32);

    f32x4 acc[4][4];
#pragma unroll
    for (int i = 0; i < 4; ++i)
#pragma unroll
        for (int j = 0; j < 4; ++j) acc[i][j] = (f32x4){0.f, 0.f, 0.f, 0.f};

    const int q15 = lane & 15;
    // swizzled read chunk: fragment row = wm + mt*16 + q15; key=(row>>1)&3
    // reduces to (q15>>1)&3 (wm and mt*16 contribute 0 mod 4 after >>1).
    const int koff = (((lane >> 4) ^ ((q15 >> 1) & 3)) * 8);

    for (int k0 = 0; k0 < 1024; k0 += 64) {
        __syncthreads();
        *(uint4*)dA0 = rA0; *(uint4*)dA1 = rA1;
        *(uint4*)dA2 = rA2; *(uint4*)dA3 = rA3;
        *(uint4*)dB0 = rB0; *(uint4*)dB1 = rB1;
        *(uint4*)dB2 = rB2; *(uint4*)dB3 = rB3;
        __syncthreads();
        if (k0 < 1024 - 64) {
            rA0 = *(const uint4*)(gA + k0 + 64);
            rA1 = *(const uint4*)(gA + k0 + 96);
            rA2 = *(const uint4*)(gA + (size_t)64 * 1024 + k0 + 64);
            rA3 = *(const uint4*)(gA + (size_t)64 * 1024 + k0 + 96);
            rB0 = *(const uint4*)(gB + k0 + 64);
            rB1 = *(const uint4*)(gB + k0 + 96);
            rB2 = *(const uint4*)(gB + (size_t)64 * 1024 + k0 + 64);
            rB3 = *(const uint4*)(gB + (size_t)64 * 1024 + k0 + 96);
        }
#pragma unroll 1
        for (int p = 0; p < 2; ++p) {
            bf16x8 af[4], bfr[4];
#pragma unroll
            for (int mt = 0; mt < 4; ++mt)
                af[mt] = *(const bf16x8*)(&sA[p][(wm + mt * 16 + q15) * 32 + koff]);
#pragma unroll
            for (int nt = 0; nt < 4; ++nt)
                bfr[nt] = *(const bf16x8*)(&sB[p][(wn + nt * 16 + q15) * 32 + koff]);
#pragma unroll
            for (int mt = 0; mt < 4; ++mt)
#pragma unroll
                for (int nt = 0; nt < 4; ++nt)
                    acc[mt][nt] = MFMA16(af[mt], bfr[nt], acc[mt][nt]);
        }
    }

    u16* outp;
    int vt;
    switch (seg) {
        case 0: outp = Qo;  vt = 0; break;
        case 1: outp = Ksa; vt = 0; break;
        case 2: outp = Vsa; vt = 1; break;
        case 3: outp = Kca; vt = 0; break;
        default: outp = Vca; vt = 1; break;
    }
    const float qs = (seg == 0) ? QSCALE : 1.0f;
    const int rq = (lane >> 4) * 4;
#pragma unroll
    for (int nt = 0; nt < 4; ++nt) {
        const int col = c8 * 128 + wn + nt * 16 + q15;
        const float bv = b2f(bias[bx * 128 + wn + nt * 16 + q15]);
#pragma unroll
        for (int mt = 0; mt < 4; ++mt) {
            const int row = m0 + wm + mt * 16 + rq;
            f32x4 v = acc[mt][nt];
            if (vt) {
                const int bb = row >> 10, tt = row & 1023;
                const int hh = col >> 6, rr = col & 63;
                const size_t idx = ((((size_t)bb * 16 + hh) * 64 + rr) << 10) + tt;
                uint2 o;
                o.x = pack2(v[0] + bv, v[1] + bv);
                o.y = pack2(v[2] + bv, v[3] + bv);
                *(uint2*)(outp + idx) = o;
            } else {
#pragma unroll
                for (int e = 0; e < 4; ++e)
                    outp[(size_t)(row + e) * 1024 + col] = f2b((v[e] + bv) * qs);
            }
        }
    }
}

// ===========================================================================
// 256x256 8-phase GEMM core (T2+T3+T4+T5 per learn_hip m194-m201/m218).
//   BM=BN=256, BK=64, 8 waves (2 M-groups x 4 N-groups), 512 threads.
//   LDS: 2 K-tile buffers x (A 256x64 + B 256x64) bf16 = 128 KiB.
//   Per K-tile: 4 phases, each {ds_read subtile | stage 1 half-tile} ->
//   s_barrier -> setprio(1) -> 16 MFMA -> setprio(0) -> s_barrier.
//   Counted vmcnt(4) once per K-tile; drained to 0 only at the last tiles.
//   Staging slot map (write-after-read-safe under the per-phase barriers):
//     B-half0(t+1) @ t.p1, B-half1(t+1) @ t.p2,
//     A-half0(t+2) @ t.p3, A-half1(t+2) @ t.p4.
//   Bank-conflict fix: chunk XOR-swizzle c ^= (row>>1)&3 applied on the
//   GLOBAL source address (gload_lds dest must stay linear) and identically
//   on the ds_read chunk -> conflict-free b128 reads (verified: 0 conflicts).
//   NOTE: only used at grids <= 256 blocks (1 block/CU) — at 320 blocks the
//   round quantization costs 1.6x (measured R1).
// ===========================================================================

#define BARR() asm volatile("s_barrier" ::: "memory")
#define VMW(N) do { asm volatile("s_waitcnt vmcnt(" #N ")" ::: "memory"); \
                    __builtin_amdgcn_sched_barrier(0); } while (0)

#define STG(ARR, GP, ROW0, T) do {                                         \
        const int b_ = (T) & 1; const int k_ = (T) * 64;                   \
        gload_lds16(GP + k_,      &ARR[b_][0][(ROW0) + wave * 16][0]);     \
        gload_lds16(GP + k_ + 32, &ARR[b_][1][(ROW0) + wave * 16][0]);     \
    } while (0)

#define LD_A(DST, ROWBASE)                                                        \
    _Pragma("unroll") for (int mf = 0; mf < 4; ++mf)                              \
    _Pragma("unroll") for (int kk = 0; kk < 2; ++kk)                              \
        DST[mf][kk] = *(const bf16x8*)&sA[buf][kk][(ROWBASE) + mf * 16 + q15][ksw];

#define LD_B(NB)                                                                  \
    _Pragma("unroll") for (int nf = 0; nf < 2; ++nf)                              \
    _Pragma("unroll") for (int kk = 0; kk < 2; ++kk)                              \
        bf[nf][kk] = *(const bf16x8*)&sB[buf][kk][wn64 + (NB) + nf * 16 + q15][ksw];

#define MFMA_PH(AF, MB, NB)                                                       \
    __builtin_amdgcn_s_setprio(1);                                                \
    _Pragma("unroll") for (int mf = 0; mf < 4; ++mf)                              \
    _Pragma("unroll") for (int nf = 0; nf < 2; ++nf)                              \
    _Pragma("unroll") for (int kk = 0; kk < 2; ++kk)                              \
        acc[(MB) + mf][(NB) + nf] =                                               \
            MFMA16(AF[mf][kk], bf[nf][kk], acc[(MB) + mf][(NB) + nf]);            \
    __builtin_amdgcn_s_setprio(0);

__device__ __forceinline__ void gemm8p_core(
    const u16* __restrict__ A, const u16* __restrict__ Bt,
    int ldK, int NT, int m0, int n0, f32x4 (&acc)[8][4])
{
    __shared__ u16 sA[2][2][256][32];   // [buf][kk-half][row][32 bf16] = 64 KiB
    __shared__ u16 sB[2][2][256][32];   // 64 KiB

    const int tid = threadIdx.x;
    const int wave = tid >> 6, lane = tid & 63;
    const int wave_m = wave >> 2;          // 0..1  (128 rows each)
    const int wave_n = wave & 3;           // 0..3  (64 cols each)
    const int q15 = lane & 15;
    const int wm128 = wave_m * 128;
    const int wn64 = wave_n * 64;
    // staging lane decomposition: 16 rows x 4 chunks of 16B per wave
    const int lrow = lane >> 2, lch = lane & 3;
    const int csw = (lch ^ ((lrow >> 1) & 3)) * 8;          // swizzled src chunk (u16)
    const int ksw = ((lane >> 4) ^ ((q15 >> 1) & 3)) * 8;   // swizzled read chunk (u16)

    const u16* gA0 = A + (size_t)(m0 + wave * 16 + lrow) * ldK + csw;
    const u16* gA1 = gA0 + (size_t)128 * ldK;
    const u16* gB0 = Bt + (size_t)(n0 + wave * 16 + lrow) * ldK + csw;
    const u16* gB1 = gB0 + (size_t)128 * ldK;

#pragma unroll
    for (int i = 0; i < 8; ++i)
#pragma unroll
        for (int j = 0; j < 4; ++j) acc[i][j] = (f32x4){0.f, 0.f, 0.f, 0.f};

    // ---- prologue: tile 0 fully + tile 1 A-halves ----
    STG(sA, gA0, 0, 0); STG(sA, gA1, 128, 0);
    STG(sB, gB0, 0, 0); STG(sB, gB1, 128, 0);
    if (NT > 1) {
        STG(sA, gA0, 0, 1); STG(sA, gA1, 128, 1);
        VMW(4);
    } else {
        VMW(0);
    }
    BARR();

    bf16x8 af0[4][2], af1[4][2], bf[2][2];

    for (int t = 0; t < NT; ++t) {
        const int buf = t & 1;
        // ---- phase 1: A rows [wm,wm+64) + B cols [wn,wn+32) ; stage B0(t+1)
        LD_A(af0, wm128);
        LD_B(0);
        if (t + 1 < NT) STG(sB, gB0, 0, t + 1);
        BARR();
        MFMA_PH(af0, 0, 0);
        BARR();
        // ---- phase 2: A rows [wm+64,wm+128) ; stage B1(t+1)
        LD_A(af1, wm128 + 64);
        if (t + 1 < NT) STG(sB, gB1, 128, t + 1);
        BARR();
        MFMA_PH(af1, 4, 0);
        BARR();
        // ---- phase 3: B cols [wn+32,wn+64) ; stage A0(t+2)
        LD_B(32);
        if (t + 2 < NT) STG(sA, gA0, 0, t + 2);
        BARR();
        MFMA_PH(af0, 0, 2);
        BARR();
        // ---- phase 4: stage A1(t+2) ; counted vmcnt at the tile boundary
        if (t + 2 < NT) {
            STG(sA, gA1, 128, t + 2);
            VMW(4);
        } else {
            VMW(0);
        }
        BARR();
        MFMA_PH(af1, 4, 2);
        BARR();
    }
}

// ---------------------------------------------------------------------------
// FFN1 on the 8-phase core: C = relu(A @ Bt^T + bias). M=4096, N=4096,
// K=1024. grid (16, 16) = 256 blocks exactly -> single round. 512 threads.
// ---------------------------------------------------------------------------
__global__ __launch_bounds__(512) void gemm8p_ffn1(
    const u16* __restrict__ A, const u16* __restrict__ Bt,
    const u16* __restrict__ bias, u16* __restrict__ C, int N, int NT)
{
    const int m0 = blockIdx.y * 256;
    const int n0 = blockIdx.x * 256;

    f32x4 acc[8][4];
    gemm8p_core(A, Bt, 1024, NT, m0, n0, acc);

    const int tid = threadIdx.x;
    const int wave = tid >> 6, lane = tid & 63;
    const int q15 = lane & 15;
    const int wm128 = (wave >> 2) * 128;
    const int wn64 = (wave & 3) * 64;
    const int rq = (lane >> 4) * 4;

#pragma unroll
    for (int nf = 0; nf < 4; ++nf) {
        const int col = n0 + wn64 + nf * 16 + q15;
        const float bv = b2f(bias[col]);
#pragma unroll
        for (int mf = 0; mf < 8; ++mf) {
            const int row = m0 + wm128 + mf * 16 + rq;
            f32x4 v = acc[mf][nf];
#pragma unroll
            for (int e = 0; e < 4; ++e)
                C[(size_t)(row + e) * N + col] = f2b(fmaxf(v[e] + bv, 0.f));
        }
    }
}

// ---------------------------------------------------------------------------
// FFN2 on the 8-phase core, split-K=3 (22/21/21 K-tiles), fp32 partials.
// M=4096, N=1024, K=4096. grid (4, 16, 3) = 192 blocks -> single round.
// z==0 adds bias.
// ---------------------------------------------------------------------------
__global__ __launch_bounds__(512) void gemm8p_ffn2(
    const u16* __restrict__ A, const u16* __restrict__ Bt,
    const u16* __restrict__ bias,
    float* __restrict__ P0, float* __restrict__ P1, float* __restrict__ P2)
{
    const int z = blockIdx.z;
    const int t0 = (z == 0) ? 0 : (22 + 21 * (z - 1));
    const int nt = (z == 0) ? 22 : 21;
    const int m0 = blockIdx.y * 256;
    const int n0 = blockIdx.x * 256;

    f32x4 acc[8][4];
    gemm8p_core(A + t0 * 64, Bt + t0 * 64, 4096, nt, m0, n0, acc);

    const int tid = threadIdx.x;
    const int wave = tid >> 6, lane = tid & 63;
    const int q15 = lane & 15;
    const int wm128 = (wave >> 2) * 128;
    const int wn64 = (wave & 3) * 64;
    const int rq = (lane >> 4) * 4;

    float* P = (z == 0) ? P0 : (z == 1) ? P1 : P2;
#pragma unroll
    for (int nf = 0; nf < 4; ++nf) {
        const int col = n0 + wn64 + nf * 16 + q15;
        const float bv = (z == 0) ? b2f(bias[col]) : 0.f;
#pragma unroll
        for (int mf = 0; mf < 8; ++mf) {
            const int row = m0 + wm128 + mf * 16 + rq;
            f32x4 v = acc[mf][nf];
#pragma unroll
            for (int e = 0; e < 4; ++e)
                P[(size_t)(row + e) * 1024 + col] = v[e] + bv;
        }
    }
}

// ---------------------------------------------------------------------------
// GEMM 64x128 tile, BK=64 panelized, global_load_lds staging (R8-verified).
// N=1024 shapes (K=1024). grid (M/64, 8). flags: 1=relu, 4=scale by QSCALE.
// ---------------------------------------------------------------------------
__global__ __launch_bounds__(256) void gemm_n1k(
    const u16* __restrict__ A, const u16* __restrict__ Bt,
    const u16* __restrict__ bias, const u16* __restrict__ resid,
    u16* __restrict__ C, int M, int N, int K, int flags)
{
    __shared__ u16 sA[2][64 * 32];
    __shared__ u16 sB[2][128 * 32];
    const int tid = threadIdx.x;
    const int wave = tid >> 6;
    const int lane = tid & 63;
    const int m0 = blockIdx.x * 64;
    const int n0 = blockIdx.y * 128;
    const int wm = (wave >> 1) * 32;
    const int wn = (wave & 1) * 64;

    const int lrow = lane >> 2;
    const int lcol = (lane & 3) * 8;
    const u16* gA = A + (size_t)(m0 + wave * 16 + lrow) * K + lcol;
    const u16* gB = Bt + (size_t)(n0 + wave * 32 + lrow) * K + lcol;
    const u16* gB2 = gB + (size_t)16 * K;
    const int lofsA = wave * 16 * 32;
    const int lofsB = wave * 32 * 32;

    f32x4 acc[2][4];
#pragma unroll
    for (int i = 0; i < 2; ++i)
#pragma unroll
        for (int j = 0; j < 4; ++j) acc[i][j] = (f32x4){0.f, 0.f, 0.f, 0.f};

    const int q15 = lane & 15;
    const int koff = (lane >> 4) * 8;

    for (int k0 = 0; k0 < K; k0 += 64) {
        __syncthreads();
        gload_lds16(gA + k0,      &sA[0][lofsA]);
        gload_lds16(gA + k0 + 32, &sA[1][lofsA]);
        gload_lds16(gB + k0,       &sB[0][lofsB]);
        gload_lds16(gB + k0 + 32,  &sB[1][lofsB]);
        gload_lds16(gB2 + k0,      &sB[0][lofsB + 16 * 32]);
        gload_lds16(gB2 + k0 + 32, &sB[1][lofsB + 16 * 32]);
        __syncthreads();
#pragma unroll 1
        for (int p = 0; p < 2; ++p) {
            bf16x8 af[2], bfr[4];
#pragma unroll
            for (int mt = 0; mt < 2; ++mt)
                af[mt] = *(const bf16x8*)(&sA[p][(wm + mt * 16 + q15) * 32 + koff]);
#pragma unroll
            for (int nt = 0; nt < 4; ++nt)
                bfr[nt] = *(const bf16x8*)(&sB[p][(wn + nt * 16 + q15) * 32 + koff]);
#pragma unroll
            for (int mt = 0; mt < 2; ++mt)
#pragma unroll
                for (int nt = 0; nt < 4; ++nt)
                    acc[mt][nt] = MFMA16(af[mt], bfr[nt], acc[mt][nt]);
        }
    }

    const int rq = (lane >> 4) * 4;
#pragma unroll
    for (int nt = 0; nt < 4; ++nt) {
        const int col = n0 + wn + nt * 16 + q15;
        const float bv = b2f(bias[col]);
#pragma unroll
        for (int mt = 0; mt < 2; ++mt) {
            const int row = m0 + wm + mt * 16 + rq;
            f32x4 v = acc[mt][nt];
#pragma unroll
            for (int e = 0; e < 4; ++e) {
                float val = v[e] + bv;
                if (flags & 1) val = fmaxf(val, 0.f);
                if (flags & 4) val *= QSCALE;
                const size_t o = (size_t)(row + e) * N + col;
                if (resid) val += b2f(resid[o]);
                C[o] = f2b(val);
            }
        }
    }
}

// ---------------------------------------------------------------------------
// Flash attention (no mask). Q,K: [B*S, H*R]; Vt: [B,H,R,S]; O: [B*S, H*R].
// R7: 128 Q rows per block (two 64-row halves share each staged K/V tile) —
// halves LDS staging traffic + barrier count per FLOP. grid 512,
// flat id = qt*64 + (b*16+h), qt in [0,8). Rows padded to 72 (2-way alias).
// Q pre-scaled by QSCALE at projection time, so P = exp2(QK) directly.
// sP reuse between halves is safe: per-wave DS ops are in-order, so half-1
// writes cannot pass half-0's pa reads; lgkmcnt(0) orders write->read.
// ---------------------------------------------------------------------------
__global__ __launch_bounds__(256) void attn_k(
    const u16* __restrict__ Q, const u16* __restrict__ K,
    const u16* __restrict__ Vt, u16* __restrict__ O)
{
    __shared__ u16 sK[64 * 72];
    __shared__ u16 sV[64 * 72];
    __shared__ u16 sP[4][16 * 72];
    const int tid = threadIdx.x, wave = tid >> 6, lane = tid & 63;
    const int q15 = lane & 15, quad = lane >> 4;
    const int bid = blockIdx.x;
    const int g = bid & 63, qt = bid >> 6;     // qt in [0,8)
    const int h = g & 15, b = g >> 4;

    const u16* qb0 = Q + ((size_t)(b * 1024 + qt * 128 + wave * 16 + q15)) * 1024 + h * 64 + quad * 8;
    const u16* qb1 = qb0 + (size_t)64 * 1024;
    bf16x8 qa[2][2];
    qa[0][0] = *(const bf16x8*)qb0;
    qa[0][1] = *(const bf16x8*)(qb0 + 32);
    qa[1][0] = *(const bf16x8*)qb1;
    qa[1][1] = *(const bf16x8*)(qb1 + 32);

    bf16x8 vone;
#pragma unroll
    for (int i = 0; i < 8; ++i) vone[i] = (__bf16)1.0f;

    f32x4 oacc[2][4];
#pragma unroll
    for (int hh = 0; hh < 2; ++hh)
#pragma unroll
        for (int i = 0; i < 4; ++i) oacc[hh][i] = (f32x4){0.f, 0.f, 0.f, 0.f};
    f32x4 lacc[2];
    lacc[0] = (f32x4){0.f, 0.f, 0.f, 0.f};
    lacc[1] = (f32x4){0.f, 0.f, 0.f, 0.f};

    const int srow = lane >> 3, scol8 = (lane & 7) * 8;
    const u16* kg = K + ((size_t)(b * 1024 + wave * 8 + srow)) * 1024 + h * 64 + scol8;
    const u16* vg = Vt + ((size_t)((b * 16 + h) * 64 + wave * 8 + srow)) * 1024 + scol8;
    u16* lKw = sK + (wave * 8 + srow) * 72 + scol8;
    u16* lVw = sV + (wave * 8 + srow) * 72 + scol8;

    uint4 k0r = *(const uint4*)kg;
    uint4 k1r = *(const uint4*)(kg + (size_t)32 * 1024);
    uint4 v0r = *(const uint4*)vg;
    uint4 v1r = *(const uint4*)(vg + (size_t)32 * 1024);

    for (int tt = 0; tt < 16; ++tt) {
        __syncthreads();
        *(uint4*)lKw = k0r;
        *(uint4*)(lKw + 32 * 72) = k1r;
        *(uint4*)lVw = v0r;
        *(uint4*)(lVw + 32 * 72) = v1r;
        __syncthreads();
        if (tt < 15) {
            const size_t t1 = (size_t)(tt + 1) * 64;
            k0r = *(const uint4*)(kg + t1 * 1024);
            k1r = *(const uint4*)(kg + t1 * 1024 + (size_t)32 * 1024);
            v0r = *(const uint4*)(vg + t1);
            v1r = *(const uint4*)(vg + t1 + (size_t)32 * 1024);
        }

#pragma unroll
        for (int hf = 0; hf < 2; ++hf) {
            f32x4 sc[4];
            __builtin_amdgcn_s_setprio(1);
#pragma unroll
            for (int nf = 0; nf < 4; ++nf) {
                bf16x8 kb0 = *(const bf16x8*)(sK + (nf * 16 + q15) * 72 + quad * 8);
                bf16x8 kb1 = *(const bf16x8*)(sK + (nf * 16 + q15) * 72 + 32 + quad * 8);
                f32x4 t = (f32x4){0.f, 0.f, 0.f, 0.f};
                t = MFMA16(qa[hf][0], kb0, t);
                t = MFMA16(qa[hf][1], kb1, t);
                sc[nf] = t;
            }
            __builtin_amdgcn_s_setprio(0);
#pragma unroll
            for (int nf = 0; nf < 4; ++nf)
#pragma unroll
                for (int e = 0; e < 4; ++e) sc[nf][e] = fexp2(sc[nf][e]);
#pragma unroll
            for (int nf = 0; nf < 4; ++nf)
#pragma unroll
                for (int e = 0; e < 4; ++e)
                    sP[wave][(quad * 4 + e) * 72 + nf * 16 + q15] = f2b(sc[nf][e]);
            asm volatile("s_waitcnt lgkmcnt(0)" ::: "memory");
            const bf16x8 pa0 = *(const bf16x8*)(sP[wave] + q15 * 72 + quad * 8);
            const bf16x8 pa1 = *(const bf16x8*)(sP[wave] + q15 * 72 + 32 + quad * 8);
            __builtin_amdgcn_s_setprio(1);
#pragma unroll
            for (int rf = 0; rf < 4; ++rf) {
                bf16x8 vb0 = *(const bf16x8*)(sV + (rf * 16 + q15) * 72 + quad * 8);
                bf16x8 vb1 = *(const bf16x8*)(sV + (rf * 16 + q15) * 72 + 32 + quad * 8);
                oacc[hf][rf] = MFMA16(pa0, vb0, oacc[hf][rf]);
                oacc[hf][rf] = MFMA16(pa1, vb1, oacc[hf][rf]);
            }
            lacc[hf] = MFMA16(pa0, vone, lacc[hf]);
            lacc[hf] = MFMA16(pa1, vone, lacc[hf]);
            __builtin_amdgcn_s_setprio(0);
        }
    }
#pragma unroll
    for (int hf = 0; hf < 2; ++hf)
#pragma unroll
        for (int rf = 0; rf < 4; ++rf)
#pragma unroll
            for (int e = 0; e < 4; ++e) {
                const float v = oacc[hf][rf][e] / lacc[hf][e];
                const size_t row = (size_t)(b * 1024 + qt * 128 + hf * 64 + wave * 16 + quad * 4 + e);
                O[row * 1024 + h * 64 + rf * 16 + q15] = f2b(v);
            }
}

// ---------------------------------------------------------------------------
// LayerNorm over last dim (1024), eps=1e-3. One wave/row, 4 rows/block.
// ---------------------------------------------------------------------------
__global__ __launch_bounds__(256) void ln_k(
    const u16* __restrict__ y, const u16* __restrict__ g,
    const u16* __restrict__ be, void* __restrict__ out, const int* __restrict__ oflag)
{
    const int f = oflag ? *oflag : 0;
    const int tid = threadIdx.x, wave = tid >> 6, lane = tid & 63;
    const size_t row = (size_t)blockIdx.x * 4 + wave;
    const u16* p = y + row * 1024 + lane * 16;
    uint4 u0 = *(const uint4*)p;
    uint4 u1 = *(const uint4*)(p + 8);
    float v[16];
    unpack8(u0, v);
    unpack8(u1, v + 8);
    float s = 0.f, s2 = 0.f;
#pragma unroll
    for (int i = 0; i < 16; ++i) { s += v[i]; s2 += v[i] * v[i]; }
#pragma unroll
    for (int off = 1; off < 64; off <<= 1) {
        s += __shfl_xor(s, off, 64);
        s2 += __shfl_xor(s2, off, 64);
    }
    const float mean = s * (1.f / 1024.f);
    const float var = s2 * (1.f / 1024.f) - mean * mean;
    const float rstd = rsqrtf(var + 1e-3f);
    uint4 g0 = *(const uint4*)(g + lane * 16);
    uint4 g1 = *(const uint4*)(g + lane * 16 + 8);
    uint4 b0 = *(const uint4*)(be + lane * 16);
    uint4 b1 = *(const uint4*)(be + lane * 16 + 8);
    float gv[16], bv[16];
    unpack8(g0, gv); unpack8(g1, gv + 8);
    unpack8(b0, bv); unpack8(b1, bv + 8);
    float w[16];
#pragma unroll
    for (int i = 0; i < 16; ++i) w[i] = (v[i] - mean) * rstd * gv[i] + bv[i];
    if (f) {
        float* q = (float*)out + row * 1024 + lane * 16;
#pragma unroll
        for (int i = 0; i < 16; i += 4)
            *(float4*)(q + i) = make_float4(w[i], w[i + 1], w[i + 2], w[i + 3]);
    } else {
        uint4 o0, o1;
        o0.x = pack2(w[0], w[1]);   o0.y = pack2(w[2], w[3]);
        o0.z = pack2(w[4], w[5]);   o0.w = pack2(w[6], w[7]);
        o1.x = pack2(w[8], w[9]);   o1.y = pack2(w[10], w[11]);
        o1.z = pack2(w[12], w[13]); o1.w = pack2(w[14], w[15]);
        u16* q = (u16*)out + row * 1024 + lane * 16;
        *(uint4*)q = o0;
        *(uint4*)(q + 8) = o1;
    }
}

// ---------------------------------------------------------------------------
// Fused split-K reduce (3 partials) + residual + LayerNorm -> d_out.
// ---------------------------------------------------------------------------
__global__ __launch_bounds__(256) void ln3f_k(
    const float* __restrict__ p0, const float* __restrict__ p1,
    const float* __restrict__ p2,
    const u16* __restrict__ resid, const u16* __restrict__ g,
    const u16* __restrict__ be, void* __restrict__ out, const int* __restrict__ oflag)
{
    const int f = *oflag;
    const int tid = threadIdx.x, wave = tid >> 6, lane = tid & 63;
    const size_t row = (size_t)blockIdx.x * 4 + wave;
    const size_t base = row * 1024 + lane * 16;
    float v[16];
#pragma unroll
    for (int i = 0; i < 16; i += 4) {
        float4 a = *(const float4*)(p0 + base + i);
        float4 b = *(const float4*)(p1 + base + i);
        float4 c = *(const float4*)(p2 + base + i);
        v[i + 0] = a.x + b.x + c.x; v[i + 1] = a.y + b.y + c.y;
        v[i + 2] = a.z + b.z + c.z; v[i + 3] = a.w + b.w + c.w;
    }
    uint4 r0 = *(const uint4*)(resid + base);
    uint4 r1 = *(const uint4*)(resid + base + 8);
    float rv[16];
    unpack8(r0, rv); unpack8(r1, rv + 8);
#pragma unroll
    for (int i = 0; i < 16; ++i) v[i] += rv[i];
    float s = 0.f, s2 = 0.f;
#pragma unroll
    for (int i = 0; i < 16; ++i) { s += v[i]; s2 += v[i] * v[i]; }
#pragma unroll
    for (int off = 1; off < 64; off <<= 1) {
        s += __shfl_xor(s, off, 64);
        s2 += __shfl_xor(s2, off, 64);
    }
    const float mean = s * (1.f / 1024.f);
    const float var = s2 * (1.f / 1024.f) - mean * mean;
    const float rstd = rsqrtf(var + 1e-3f);
    uint4 g0 = *(const uint4*)(g + lane * 16);
    uint4 g1 = *(const uint4*)(g + lane * 16 + 8);
    uint4 b0 = *(const uint4*)(be + lane * 16);
    uint4 b1 = *(const uint4*)(be + lane * 16 + 8);
    float gv[16], bv[16];
    unpack8(g0, gv); unpack8(g1, gv + 8);
    unpack8(b0, bv); unpack8(b1, bv + 8);
    float w[16];
#pragma unroll
    for (int i = 0; i < 16; ++i) w[i] = (v[i] - mean) * rstd * gv[i] + bv[i];
    if (f) {
        float* q = (float*)out + base;
#pragma unroll
        for (int i = 0; i < 16; i += 4)
            *(float4*)(q + i) = make_float4(w[i], w[i + 1], w[i + 2], w[i + 3]);
    } else {
        uint4 o0, o1;
        o0.x = pack2(w[0], w[1]);   o0.y = pack2(w[2], w[3]);
        o0.z = pack2(w[4], w[5]);   o0.w = pack2(w[6], w[7]);
        o1.x = pack2(w[8], w[9]);   o1.y = pack2(w[10], w[11]);
        o1.z = pack2(w[12], w[13]); o1.w = pack2(w[14], w[15]);
        u16* q = (u16*)out + base;
        *(uint4*)q = o0;
        *(uint4*)(q + 8) = o1;
    }
}

// ---------------------------------------------------------------------------
extern "C" void kernel_launch(void* const* d_in, const int* in_sizes, int n_in,
                              void* d_out, int out_size, void* d_ws, size_t ws_size,
                              hipStream_t stream)
{
    (void)in_sizes; (void)n_in; (void)out_size; (void)ws_size;
    const void* x   = d_in[0];
    const void* ctx = d_in[1];

    u16* ws = (u16*)d_ws;
    const size_t MEG = 1u << 20;
    u16* wT      = ws;               // 0..16M elems: transposed weights
    u16* bufx    = ws + 16 * MEG;
    u16* bufctx  = ws + 20 * MEG;
    u16* bufq    = ws + 24 * MEG;
    u16* bufk_sa = ws + 28 * MEG;
    u16* bufvt_sa= ws + 32 * MEG;
    u16* bufk_ca = ws + 36 * MEG;
    u16* bufvt_ca= ws + 40 * MEG;
    u16* bufo    = ws + 44 * MEG;
    u16* bufln   = ws + 48 * MEG;
    u16* small   = ws + 52 * MEG;
    int* flag    = (int*)(small + 20480);
    u16* bufh    = ws + 16 * MEG;    // FFN hidden (16..32M; bufx/ctx/q/k_sa dead)
    // split-K=3 fp32 partials (each 4096x1024 f32 = 16 MB = 8M u16):
    //  p0: 32..40M (bufvt_sa dead), p1: 40..48M (bufvt_ca/bufo dead),
    //  p2: 4..12M (wT[4..12M] all consumed before FFN2; wT[12..16M] stays live)
    float* part0 = (float*)(ws + 32 * MEG);
    float* part1 = (float*)(ws + 40 * MEG);
    float* part2 = (float*)(ws + 4 * MEG);

    const int O_SABQ = 0,    O_SABK = 1024, O_SABV = 2048;
    const int O_CABK = 3072, O_CABV = 4096, O_CABQ = 5120;
    const int O_SABO = 6144, O_CABO = 7168;
    const int O_L1G = 8192,  O_L1B = 9216,  O_L2G = 10240, O_L2B = 11264;
    const int O_L3G = 12288, O_L3B = 13312, O_FB1 = 14336, O_FB2 = 18432;

    PtrTab tab;
    const void* sp[16] = { d_in[3], d_in[5], d_in[7], d_in[13], d_in[15], d_in[11],
                           d_in[9], d_in[17],
                           d_in[18], d_in[19], d_in[20], d_in[21], d_in[22], d_in[23],
                           d_in[25], d_in[27] };
    const int so[16] = { O_SABQ, O_SABK, O_SABV, O_CABK, O_CABV, O_CABQ, O_SABO, O_CABO,
                         O_L1G, O_L1B, O_L2G, O_L2B, O_L3G, O_L3B, O_FB1, O_FB2 };
    const int sc[16] = { 1024, 1024, 1024, 1024, 1024, 1024, 1024, 1024,
                         1024, 1024, 1024, 1024, 1024, 1024, 4096, 1024 };
    for (int i = 0; i < 16; ++i) { tab.p[i] = sp[i]; tab.off[i] = so[i]; tab.cnt[i] = sc[i]; }

    PtrTab tab6;
    const void* wp[6] = { d_in[2], d_in[4], d_in[6], d_in[12], d_in[14], d_in[10] };
    for (int i = 0; i < 6; ++i) tab6.p[i] = wp[i];

    const dim3 blk(256);
    const dim3 blk8(512);
    const dim3 gN1(64, 8);

    // ---- dtype normalize + weight prep (R6-verified chain) ----
    detect_k<<<1, blk, 0, stream>>>((const u32*)x, flag);
    conv2_k<<<dim3(2048, 2), blk, 0, stream>>>(x, ctx, bufx, bufctx, 4 * MEG, flag);
    conv_small_k<<<dim3(16), blk, 0, stream>>>(tab, small, flag);
    transpose6_k<<<dim3(1, 16, 96), blk, 0, stream>>>(tab6, wT, flag);
    transpose_k<<<dim3(16, 16), blk, 0, stream>>>(d_in[8],  wT + 6 * MEG, 1024, 1024, flag);
    transpose_k<<<dim3(16, 16), blk, 0, stream>>>(d_in[16], wT + 7 * MEG, 1024, 1024, flag);
    transpose_k<<<dim3(64, 16), blk, 0, stream>>>(d_in[24], wT + 8 * MEG, 1024, 4096, flag);
    transpose_k<<<dim3(16, 64), blk, 0, stream>>>(d_in[26], wT + 12 * MEG, 4096, 1024, flag);

    // ---- fused projections (SA-Q pre-scaled by QSCALE) ----
    gemm_qkv_k<<<dim3(40, 32), blk, 0, stream>>>(bufx, bufctx, wT, small,
                                                 bufq, bufk_sa, bufvt_sa, bufk_ca, bufvt_ca);

    // ---- self-attention (128 Q rows/block -> grid 512) ----
    attn_k<<<dim3(512), blk, 0, stream>>>(bufq, bufk_sa, bufvt_sa, bufo);
    gemm_n1k<<<gN1, blk, 0, stream>>>(bufo, wT + 6 * MEG, small + O_SABO, bufx,
                                      bufq, 4096, 1024, 1024, 0);
    ln_k<<<dim3(1024), blk, 0, stream>>>(bufq, small + O_L1G, small + O_L1B, bufln, nullptr);

    // ---- cross-attention (CA-Q pre-scaled via flags|4) ----
    gemm_n1k<<<gN1, blk, 0, stream>>>(bufln, wT + 5 * MEG, small + O_CABQ, nullptr,
                                      bufq, 4096, 1024, 1024, 4);
    attn_k<<<dim3(512), blk, 0, stream>>>(bufq, bufk_ca, bufvt_ca, bufo);
    gemm_n1k<<<gN1, blk, 0, stream>>>(bufo, wT + 7 * MEG, small + O_CABO, bufln,
                                      bufq, 4096, 1024, 1024, 0);
    ln_k<<<dim3(1024), blk, 0, stream>>>(bufq, small + O_L2G, small + O_L2B, bufln, nullptr);

    // ---- FFN (256^2 8-phase; FFN2 split-K=3 + fused reduce/LN) ----
    gemm8p_ffn1<<<dim3(16, 16), blk8, 0, stream>>>(bufln, wT + 8 * MEG, small + O_FB1,
                                                   bufh, 4096, 16);
    gemm8p_ffn2<<<dim3(4, 16, 3), blk8, 0, stream>>>(bufh, wT + 12 * MEG, small + O_FB2,
                                                     part0, part1, part2);
    ln3f_k<<<dim3(1024), blk, 0, stream>>>(part0, part1, part2, bufln,
                                           small + O_L3G, small + O_L3B, d_out, flag);
}

// Round 8
// 494.474 us; speedup vs baseline: 1.0579x; 1.0432x over previous
//
#include <hip/hip_runtime.h>
#include <math.h>

typedef unsigned short u16;
typedef unsigned int u32;
typedef __bf16 bf16x8 __attribute__((ext_vector_type(8)));
typedef float f32x4 __attribute__((ext_vector_type(4)));

#define MFMA16(a, b, c) __builtin_amdgcn_mfma_f32_16x16x32_bf16(a, b, c, 0, 0, 0)

// QSCALE = (1/sqrt(64)) * log2(e): folded into Q at projection time so the
// attention inner loop needs only v_exp_f32 (2^x).
#define QSCALE 0.1803368801111204f

typedef __attribute__((address_space(1))) void gvoid;
typedef __attribute__((address_space(3))) void lvoid;

__device__ __forceinline__ void gload_lds16(const void* g, void* l) {
    __builtin_amdgcn_global_load_lds((gvoid*)g, (lvoid*)l, 16, 0, 0);
}

__device__ __forceinline__ float fexp2(float x) {
#if __has_builtin(__builtin_amdgcn_exp2f)
    return __builtin_amdgcn_exp2f(x);
#else
    return __expf(x * 0.6931471805599453f);
#endif
}

__device__ __forceinline__ float b2f(u16 u) {
    union { u32 i; float f; } w;
    w.i = ((u32)u) << 16;
    return w.f;
}

__device__ __forceinline__ u16 f2b(float f) {
    union { float f; u32 i; } w;
    w.f = f;
    u32 x = w.i;
    u32 r = (x + 0x7fffu + ((x >> 16) & 1u)) >> 16;  // RNE
    return (u16)r;
}

__device__ __forceinline__ void unpack8(uint4 u, float* v) {
    v[0] = b2f((u16)(u.x & 0xffff)); v[1] = b2f((u16)(u.x >> 16));
    v[2] = b2f((u16)(u.y & 0xffff)); v[3] = b2f((u16)(u.y >> 16));
    v[4] = b2f((u16)(u.z & 0xffff)); v[5] = b2f((u16)(u.z >> 16));
    v[6] = b2f((u16)(u.w & 0xffff)); v[7] = b2f((u16)(u.w >> 16));
}

__device__ __forceinline__ u32 pack2(float a, float b) {
    return (u32)f2b(a) | ((u32)f2b(b) << 16);
}

// ---------------------------------------------------------------------------
// Input dtype detector: flag=1 -> fp32 inputs.
// ---------------------------------------------------------------------------
__global__ __launch_bounds__(256) void detect_k(const u32* __restrict__ x, int* __restrict__ flag)
{
    __shared__ int cnt[256];
    int c = 0;
#pragma unroll 4
    for (int i = 0; i < 256; ++i) {
        const u32 w = x[threadIdx.x * 256 + i];
        const u32 e = (w >> 7) & 0xFF;
        c += (e < 0x20 || e > 0x4F) ? 1 : 0;
    }
    cnt[threadIdx.x] = c;
    __syncthreads();
    if (threadIdx.x == 0) {
        int t = 0;
        for (int i = 0; i < 256; ++i) t += cnt[i];
        *flag = (t > 16384) ? 1 : 0;
    }
}

struct PtrTab {
    const void* p[16];
    int off[16];
    int cnt[16];
};

// ---------------------------------------------------------------------------
// R8: fused prep kernel — one dispatch replaces conv2_k + conv_small_k +
// transpose6_k + 4x transpose_k (7 launches -> 1; each launch costs ~10us of
// fixed overhead per the R7 accounting: sum-of-rooflines ~300us vs total 516).
// Flat block-ID dispatcher; per-block work is byte-identical to the old
// kernels; all branches are block-uniform (no divergent barriers).
//   [0, 4096)        conv2     (x/ctx -> bufx/bufctx)
//   [4096, 4112)     conv_small (16 small tensors -> small)
//   [4112, 5648)     transpose6 (6 head-blocked weights -> wT[0..6M))
//   [5648, 5904)     transpose d_in[8]  -> wT+6M  (1024x1024)
//   [5904, 6160)     transpose d_in[16] -> wT+7M  (1024x1024)
//   [6160, 7184)     transpose d_in[24] -> wT+8M  (1024x4096)
//   [7184, 8208)     transpose d_in[26] -> wT+12M (4096x1024)
// ---------------------------------------------------------------------------
__device__ __forceinline__ void transpose_body(
    const void* __restrict__ in, u16* __restrict__ out, int rows, int cols,
    int bx, int by, int f, u16 (*t)[65], int tid)
{
    const int lr = tid >> 4;
    const int lc = (tid & 15) * 4;
    const int r0 = by * 64, c0 = bx * 64;
#pragma unroll
    for (int i = 0; i < 4; ++i) {
        const size_t off = (size_t)(r0 + i * 16 + lr) * cols + c0 + lc;
        if (f) {
            const float* p = (const float*)in + off;
            t[i * 16 + lr][lc + 0] = f2b(p[0]);
            t[i * 16 + lr][lc + 1] = f2b(p[1]);
            t[i * 16 + lr][lc + 2] = f2b(p[2]);
            t[i * 16 + lr][lc + 3] = f2b(p[3]);
        } else {
            const u16* p = (const u16*)in + off;
            t[i * 16 + lr][lc + 0] = p[0];
            t[i * 16 + lr][lc + 1] = p[1];
            t[i * 16 + lr][lc + 2] = p[2];
            t[i * 16 + lr][lc + 3] = p[3];
        }
    }
    __syncthreads();
#pragma unroll
    for (int i = 0; i < 4; ++i) {
        const int rr = i * 16 + lr;
        uint2 o;
        o.x = (u32)t[lc + 0][rr] | ((u32)t[lc + 1][rr] << 16);
        o.y = (u32)t[lc + 2][rr] | ((u32)t[lc + 3][rr] << 16);
        *(uint2*)(out + (size_t)(c0 + rr) * rows + r0 + lc) = o;
    }
}

__global__ __launch_bounds__(256) void prep_k(
    const void* __restrict__ x, const void* __restrict__ ctx,
    u16* __restrict__ bufx, u16* __restrict__ bufctx,
    PtrTab tab, u16* __restrict__ small,
    PtrTab tab6, u16* __restrict__ wT,
    const void* __restrict__ w8, const void* __restrict__ w16,
    const void* __restrict__ w24, const void* __restrict__ w26,
    const int* __restrict__ flag)
{
    const int f = *flag;
    const int tid = threadIdx.x;
    const size_t MEG = 1u << 20;
    __shared__ u16 t[64][65];
    int id = blockIdx.x;

    if (id < 4096) {
        // ---- conv2: x and ctx fp32->bf16 (or copy) ----
        const void* in = (id >= 2048) ? ctx : x;
        u16* out = (id >= 2048) ? bufctx : bufx;
        const int i = ((id & 2047) * 256 + tid) * 8;
        if (f) {
            const float* p = (const float*)in + i;
            uint4 o;
            o.x = pack2(p[0], p[1]); o.y = pack2(p[2], p[3]);
            o.z = pack2(p[4], p[5]); o.w = pack2(p[6], p[7]);
            *(uint4*)(out + i) = o;
        } else {
            *(uint4*)(out + i) = *(const uint4*)((const u16*)in + i);
        }
        return;
    }
    id -= 4096;
    if (id < 16) {
        // ---- conv_small: biases + LN params ----
        const void* src = tab.p[id];
        const int n = tab.cnt[id];
        u16* dst = small + tab.off[id];
        for (int i = tid; i < n; i += 256)
            dst[i] = f ? f2b(((const float*)src)[i]) : ((const u16*)src)[i];
        return;
    }
    id -= 16;
    if (id < 1536) {
        // ---- transpose6: head-blocked weights [16,1024,64] -> [1024,1024] ----
        const int z = id >> 4, y = id & 15;
        const int w = z >> 4, h = z & 15;
        const void* in = tab6.p[w];
        u16* out = wT + (size_t)w * MEG + h * 65536;
        const size_t ibase = (size_t)h * 65536;
        const int r0 = y * 64;
        const int lr = tid >> 4;
        const int lc = (tid & 15) * 4;
#pragma unroll
        for (int i = 0; i < 4; ++i) {
            const size_t off = ibase + (size_t)(r0 + i * 16 + lr) * 64 + lc;
            if (f) {
                const float* p = (const float*)in + off;
                t[i * 16 + lr][lc + 0] = f2b(p[0]);
                t[i * 16 + lr][lc + 1] = f2b(p[1]);
                t[i * 16 + lr][lc + 2] = f2b(p[2]);
                t[i * 16 + lr][lc + 3] = f2b(p[3]);
            } else {
                const u16* p = (const u16*)in + off;
                t[i * 16 + lr][lc + 0] = p[0];
                t[i * 16 + lr][lc + 1] = p[1];
                t[i * 16 + lr][lc + 2] = p[2];
                t[i * 16 + lr][lc + 3] = p[3];
            }
        }
        __syncthreads();
#pragma unroll
        for (int i = 0; i < 4; ++i) {
            const int rr = i * 16 + lr;
            uint2 o;
            o.x = (u32)t[lc + 0][rr] | ((u32)t[lc + 1][rr] << 16);
            o.y = (u32)t[lc + 2][rr] | ((u32)t[lc + 3][rr] << 16);
            *(uint2*)(out + (size_t)rr * 1024 + r0 + lc) = o;
        }
        return;
    }
    id -= 1536;
    if (id < 256) {
        transpose_body(w8, wT + 6 * MEG, 1024, 1024, id & 15, id >> 4, f, t, tid);
        return;
    }
    id -= 256;
    if (id < 256) {
        transpose_body(w16, wT + 7 * MEG, 1024, 1024, id & 15, id >> 4, f, t, tid);
        return;
    }
    id -= 256;
    if (id < 1024) {
        transpose_body(w24, wT + 8 * MEG, 1024, 4096, id % 64, id / 64, f, t, tid);
        return;
    }
    id -= 1024;
    transpose_body(w26, wT + 12 * MEG, 4096, 1024, id % 16, id / 16, f, t, tid);
}

// ---------------------------------------------------------------------------
// Grouped projection GEMM, BK=64 panelized, register-prefetch staging.
// M=4096, K=1024. grid (40, 32). SA-Q output pre-scaled by QSCALE (fp32).
// R5/R6 verdicts: LDS chunk XOR-swizzle KEPT (conflicts 5.24M->0);
// XCD remap refuted+reverted (FETCH 81->90.5MB). Near structure ceiling.
// ---------------------------------------------------------------------------
__global__ __launch_bounds__(256) void gemm_qkv_k(
    const u16* __restrict__ X, const u16* __restrict__ CTX,
    const u16* __restrict__ wT, const u16* __restrict__ bias,
    u16* __restrict__ Qo, u16* __restrict__ Ksa, u16* __restrict__ Vsa,
    u16* __restrict__ Kca, u16* __restrict__ Vca)
{
    __shared__ u16 sA[2][128 * 32];
    __shared__ u16 sB[2][128 * 32];
    const int tid = threadIdx.x;
    const int wave = tid >> 6;
    const int lane = tid & 63;

    const int bx = blockIdx.x;
    const int by = blockIdx.y;

    const int seg = bx >> 3, c8 = bx & 7;
    const int m0 = by * 128;
    const int wm = (wave >> 1) * 64;
    const int wn = (wave & 1) * 64;
    const u16* A = (seg < 3) ? X : CTX;

    const int lrow = lane >> 2;
    const int lcol = (lane & 3) * 8;
    const u16* gA = A + (size_t)(m0 + wave * 16 + lrow) * 1024 + lcol;
    const u16* gB = wT + (size_t)(bx * 128 + wave * 16 + lrow) * 1024 + lcol;
    const int lofs = wave * 16 * 32;
    // swizzled write chunk: row within buffer = wave*16+lrow; key=(row>>1)&3
    // == (lrow>>1)&3 since wave*16>>1 is 0 mod 4.
    const int wsw = lofs + lrow * 32 + (((lane & 3) ^ ((lrow >> 1) & 3)) * 8);

    u16* dA0 = &sA[0][wsw];
    u16* dA1 = &sA[1][wsw];
    u16* dA2 = &sA[0][64 * 32 + wsw];
    u16* dA3 = &sA[1][64 * 32 + wsw];
    u16* dB0 = &sB[0][wsw];
    u16* dB1 = &sB[1][wsw];
    u16* dB2 = &sB[0][64 * 32 + wsw];
    u16* dB3 = &sB[1][64 * 32 + wsw];

    uint4 rA0 = *(const uint4*)(gA);
    uint4 rA1 = *(const uint4*)(gA + 32);
    uint4 rA2 = *(const uint4*)(gA + (size_t)64 * 1024);
    uint4 rA3 = *(const uint4*)(gA + (size_t)64 * 1024 + 32);
    uint4 rB0 = *(const uint4*)(gB);
    uint4 rB1 = *(const uint4*)(gB + 32);
    uint4 rB2 = *(const uint4*)(gB + (size_t)64 * 1024);
    uint4 rB3 = *(const uint4*)(gB + (size_t)64 * 1024 + 32);

    f32x4 acc[4][4];
#pragma unroll
    for (int i = 0; i < 4; ++i)
#pragma unroll
        for (int j = 0; j < 4; ++j) acc[i][j] = (f32x4){0.f, 0.f, 0.f, 0.f};

    const int q15 = lane & 15;
    // swizzled read chunk: fragment row = wm + mt*16 + q15; key=(row>>1)&3
    // reduces to (q15>>1)&3 (wm and mt*16 contribute 0 mod 4 after >>1).
    const int koff = (((lane >> 4) ^ ((q15 >> 1) & 3)) * 8);

    for (int k0 = 0; k0 < 1024; k0 += 64) {
        __syncthreads();
        *(uint4*)dA0 = rA0; *(uint4*)dA1 = rA1;
        *(uint4*)dA2 = rA2; *(uint4*)dA3 = rA3;
        *(uint4*)dB0 = rB0; *(uint4*)dB1 = rB1;
        *(uint4*)dB2 = rB2; *(uint4*)dB3 = rB3;
        __syncthreads();
        if (k0 < 1024 - 64) {
            rA0 = *(const uint4*)(gA + k0 + 64);
            rA1 = *(const uint4*)(gA + k0 + 96);
            rA2 = *(const uint4*)(gA + (size_t)64 * 1024 + k0 + 64);
            rA3 = *(const uint4*)(gA + (size_t)64 * 1024 + k0 + 96);
            rB0 = *(const uint4*)(gB + k0 + 64);
            rB1 = *(const uint4*)(gB + k0 + 96);
            rB2 = *(const uint4*)(gB + (size_t)64 * 1024 + k0 + 64);
            rB3 = *(const uint4*)(gB + (size_t)64 * 1024 + k0 + 96);
        }
#pragma unroll 1
        for (int p = 0; p < 2; ++p) {
            bf16x8 af[4], bfr[4];
#pragma unroll
            for (int mt = 0; mt < 4; ++mt)
                af[mt] = *(const bf16x8*)(&sA[p][(wm + mt * 16 + q15) * 32 + koff]);
#pragma unroll
            for (int nt = 0; nt < 4; ++nt)
                bfr[nt] = *(const bf16x8*)(&sB[p][(wn + nt * 16 + q15) * 32 + koff]);
#pragma unroll
            for (int mt = 0; mt < 4; ++mt)
#pragma unroll
                for (int nt = 0; nt < 4; ++nt)
                    acc[mt][nt] = MFMA16(af[mt], bfr[nt], acc[mt][nt]);
        }
    }

    u16* outp;
    int vt;
    switch (seg) {
        case 0: outp = Qo;  vt = 0; break;
        case 1: outp = Ksa; vt = 0; break;
        case 2: outp = Vsa; vt = 1; break;
        case 3: outp = Kca; vt = 0; break;
        default: outp = Vca; vt = 1; break;
    }
    const float qs = (seg == 0) ? QSCALE : 1.0f;
    const int rq = (lane >> 4) * 4;
#pragma unroll
    for (int nt = 0; nt < 4; ++nt) {
        const int col = c8 * 128 + wn + nt * 16 + q15;
        const float bv = b2f(bias[bx * 128 + wn + nt * 16 + q15]);
#pragma unroll
        for (int mt = 0; mt < 4; ++mt) {
            const int row = m0 + wm + mt * 16 + rq;
            f32x4 v = acc[mt][nt];
            if (vt) {
                const int bb = row >> 10, tt = row & 1023;
                const int hh = col >> 6, rr = col & 63;
                const size_t idx = ((((size_t)bb * 16 + hh) * 64 + rr) << 10) + tt;
                uint2 o;
                o.x = pack2(v[0] + bv, v[1] + bv);
                o.y = pack2(v[2] + bv, v[3] + bv);
                *(uint2*)(outp + idx) = o;
            } else {
#pragma unroll
                for (int e = 0; e < 4; ++e)
                    outp[(size_t)(row + e) * 1024 + col] = f2b((v[e] + bv) * qs);
            }
        }
    }
}

// ===========================================================================
// 256x256 8-phase GEMM core (T2+T3+T4+T5 per learn_hip m194-m201/m218).
//   BM=BN=256, BK=64, 8 waves (2 M-groups x 4 N-groups), 512 threads.
//   LDS: 2 K-tile buffers x (A 256x64 + B 256x64) bf16 = 128 KiB.
//   Per K-tile: 4 phases, each {ds_read subtile | stage 1 half-tile} ->
//   s_barrier -> setprio(1) -> 16 MFMA -> setprio(0) -> s_barrier.
//   Counted vmcnt(4) once per K-tile; drained to 0 only at the last tiles.
//   Bank-conflict fix: chunk XOR-swizzle on global source + ds_read chunk.
//   NOTE: only used at grids <= 256 blocks (1 block/CU).
// ===========================================================================

#define BARR() asm volatile("s_barrier" ::: "memory")
#define VMW(N) do { asm volatile("s_waitcnt vmcnt(" #N ")" ::: "memory"); \
                    __builtin_amdgcn_sched_barrier(0); } while (0)

#define STG(ARR, GP, ROW0, T) do {                                         \
        const int b_ = (T) & 1; const int k_ = (T) * 64;                   \
        gload_lds16(GP + k_,      &ARR[b_][0][(ROW0) + wave * 16][0]);     \
        gload_lds16(GP + k_ + 32, &ARR[b_][1][(ROW0) + wave * 16][0]);     \
    } while (0)

#define LD_A(DST, ROWBASE)                                                        \
    _Pragma("unroll") for (int mf = 0; mf < 4; ++mf)                              \
    _Pragma("unroll") for (int kk = 0; kk < 2; ++kk)                              \
        DST[mf][kk] = *(const bf16x8*)&sA[buf][kk][(ROWBASE) + mf * 16 + q15][ksw];

#define LD_B(NB)                                                                  \
    _Pragma("unroll") for (int nf = 0; nf < 2; ++nf)                              \
    _Pragma("unroll") for (int kk = 0; kk < 2; ++kk)                              \
        bf[nf][kk] = *(const bf16x8*)&sB[buf][kk][wn64 + (NB) + nf * 16 + q15][ksw];

#define MFMA_PH(AF, MB, NB)                                                       \
    __builtin_amdgcn_s_setprio(1);                                                \
    _Pragma("unroll") for (int mf = 0; mf < 4; ++mf)                              \
    _Pragma("unroll") for (int nf = 0; nf < 2; ++nf)                              \
    _Pragma("unroll") for (int kk = 0; kk < 2; ++kk)                              \
        acc[(MB) + mf][(NB) + nf] =                                               \
            MFMA16(AF[mf][kk], bf[nf][kk], acc[(MB) + mf][(NB) + nf]);            \
    __builtin_amdgcn_s_setprio(0);

__device__ __forceinline__ void gemm8p_core(
    const u16* __restrict__ A, const u16* __restrict__ Bt,
    int ldK, int NT, int m0, int n0, f32x4 (&acc)[8][4])
{
    __shared__ u16 sA[2][2][256][32];   // [buf][kk-half][row][32 bf16] = 64 KiB
    __shared__ u16 sB[2][2][256][32];   // 64 KiB

    const int tid = threadIdx.x;
    const int wave = tid >> 6, lane = tid & 63;
    const int q15 = lane & 15;
    // staging lane decomposition: 16 rows x 4 chunks of 16B per wave
    const int lrow = lane >> 2, lch = lane & 3;
    const int csw = (lch ^ ((lrow >> 1) & 3)) * 8;          // swizzled src chunk (u16)
    const int ksw = ((lane >> 4) ^ ((q15 >> 1) & 3)) * 8;   // swizzled read chunk (u16)
    const int wn64 = (wave & 3) * 64;
    const int wm128 = (wave >> 2) * 128;

    const u16* gA0 = A + (size_t)(m0 + wave * 16 + lrow) * ldK + csw;
    const u16* gA1 = gA0 + (size_t)128 * ldK;
    const u16* gB0 = Bt + (size_t)(n0 + wave * 16 + lrow) * ldK + csw;
    const u16* gB1 = gB0 + (size_t)128 * ldK;

#pragma unroll
    for (int i = 0; i < 8; ++i)
#pragma unroll
        for (int j = 0; j < 4; ++j) acc[i][j] = (f32x4){0.f, 0.f, 0.f, 0.f};

    // ---- prologue: tile 0 fully + tile 1 A-halves ----
    STG(sA, gA0, 0, 0); STG(sA, gA1, 128, 0);
    STG(sB, gB0, 0, 0); STG(sB, gB1, 128, 0);
    if (NT > 1) {
        STG(sA, gA0, 0, 1); STG(sA, gA1, 128, 1);
        VMW(4);
    } else {
        VMW(0);
    }
    BARR();

    bf16x8 af0[4][2], af1[4][2], bf[2][2];

    for (int t = 0; t < NT; ++t) {
        const int buf = t & 1;
        // ---- phase 1: A rows [wm,wm+64) + B cols [wn,wn+32) ; stage B0(t+1)
        LD_A(af0, wm128);
        LD_B(0);
        if (t + 1 < NT) STG(sB, gB0, 0, t + 1);
        BARR();
        MFMA_PH(af0, 0, 0);
        BARR();
        // ---- phase 2: A rows [wm+64,wm+128) ; stage B1(t+1)
        LD_A(af1, wm128 + 64);
        if (t + 1 < NT) STG(sB, gB1, 128, t + 1);
        BARR();
        MFMA_PH(af1, 4, 0);
        BARR();
        // ---- phase 3: B cols [wn+32,wn+64) ; stage A0(t+2)
        LD_B(32);
        if (t + 2 < NT) STG(sA, gA0, 0, t + 2);
        BARR();
        MFMA_PH(af0, 0, 2);
        BARR();
        // ---- phase 4: stage A1(t+2) ; counted vmcnt at the tile boundary
        if (t + 2 < NT) {
            STG(sA, gA1, 128, t + 2);
            VMW(4);
        } else {
            VMW(0);
        }
        BARR();
        MFMA_PH(af1, 4, 2);
        BARR();
    }
}

// ---------------------------------------------------------------------------
// FFN1 on the 8-phase core: C = relu(A @ Bt^T + bias). M=4096, N=4096,
// K=1024. grid (16, 16) = 256 blocks exactly -> single round. 512 threads.
// ---------------------------------------------------------------------------
__global__ __launch_bounds__(512) void gemm8p_ffn1(
    const u16* __restrict__ A, const u16* __restrict__ Bt,
    const u16* __restrict__ bias, u16* __restrict__ C, int N, int NT)
{
    const int m0 = blockIdx.y * 256;
    const int n0 = blockIdx.x * 256;

    f32x4 acc[8][4];
    gemm8p_core(A, Bt, 1024, NT, m0, n0, acc);

    const int tid = threadIdx.x;
    const int wave = tid >> 6, lane = tid & 63;
    const int q15 = lane & 15;
    const int wm128 = (wave >> 2) * 128;
    const int wn64 = (wave & 3) * 64;
    const int rq = (lane >> 4) * 4;

#pragma unroll
    for (int nf = 0; nf < 4; ++nf) {
        const int col = n0 + wn64 + nf * 16 + q15;
        const float bv = b2f(bias[col]);
#pragma unroll
        for (int mf = 0; mf < 8; ++mf) {
            const int row = m0 + wm128 + mf * 16 + rq;
            f32x4 v = acc[mf][nf];
#pragma unroll
            for (int e = 0; e < 4; ++e)
                C[(size_t)(row + e) * N + col] = f2b(fmaxf(v[e] + bv, 0.f));
        }
    }
}

// ---------------------------------------------------------------------------
// FFN2 on the 8-phase core, split-K=3 (22/21/21 K-tiles), fp32 partials.
// M=4096, N=1024, K=4096. grid (4, 16, 3) = 192 blocks -> single round.
// z==0 adds bias.
// ---------------------------------------------------------------------------
__global__ __launch_bounds__(512) void gemm8p_ffn2(
    const u16* __restrict__ A, const u16* __restrict__ Bt,
    const u16* __restrict__ bias,
    float* __restrict__ P0, float* __restrict__ P1, float* __restrict__ P2)
{
    const int z = blockIdx.z;
    const int t0 = (z == 0) ? 0 : (22 + 21 * (z - 1));
    const int nt = (z == 0) ? 22 : 21;
    const int m0 = blockIdx.y * 256;
    const int n0 = blockIdx.x * 256;

    f32x4 acc[8][4];
    gemm8p_core(A + t0 * 64, Bt + t0 * 64, 4096, nt, m0, n0, acc);

    const int tid = threadIdx.x;
    const int wave = tid >> 6, lane = tid & 63;
    const int q15 = lane & 15;
    const int wm128 = (wave >> 2) * 128;
    const int wn64 = (wave & 3) * 64;
    const int rq = (lane >> 4) * 4;

    float* P = (z == 0) ? P0 : (z == 1) ? P1 : P2;
#pragma unroll
    for (int nf = 0; nf < 4; ++nf) {
        const int col = n0 + wn64 + nf * 16 + q15;
        const float bv = (z == 0) ? b2f(bias[col]) : 0.f;
#pragma unroll
        for (int mf = 0; mf < 8; ++mf) {
            const int row = m0 + wm128 + mf * 16 + rq;
            f32x4 v = acc[mf][nf];
#pragma unroll
            for (int e = 0; e < 4; ++e)
                P[(size_t)(row + e) * 1024 + col] = v[e] + bv;
        }
    }
}

// ---------------------------------------------------------------------------
// GEMM 64x128 tile, BK=64 panelized, global_load_lds staging (R8-verified).
// N=1024 shapes (K=1024). grid (M/64, 8). flags: 1=relu, 4=scale by QSCALE.
// ---------------------------------------------------------------------------
__global__ __launch_bounds__(256) void gemm_n1k(
    const u16* __restrict__ A, const u16* __restrict__ Bt,
    const u16* __restrict__ bias, const u16* __restrict__ resid,
    u16* __restrict__ C, int M, int N, int K, int flags)
{
    __shared__ u16 sA[2][64 * 32];
    __shared__ u16 sB[2][128 * 32];
    const int tid = threadIdx.x;
    const int wave = tid >> 6;
    const int lane = tid & 63;
    const int m0 = blockIdx.x * 64;
    const int n0 = blockIdx.y * 128;
    const int wm = (wave >> 1) * 32;
    const int wn = (wave & 1) * 64;

    const int lrow = lane >> 2;
    const int lcol = (lane & 3) * 8;
    const u16* gA = A + (size_t)(m0 + wave * 16 + lrow) * K + lcol;
    const u16* gB = Bt + (size_t)(n0 + wave * 32 + lrow) * K + lcol;
    const u16* gB2 = gB + (size_t)16 * K;
    const int lofsA = wave * 16 * 32;
    const int lofsB = wave * 32 * 32;

    f32x4 acc[2][4];
#pragma unroll
    for (int i = 0; i < 2; ++i)
#pragma unroll
        for (int j = 0; j < 4; ++j) acc[i][j] = (f32x4){0.f, 0.f, 0.f, 0.f};

    const int q15 = lane & 15;
    const int koff = (lane >> 4) * 8;

    for (int k0 = 0; k0 < K; k0 += 64) {
        __syncthreads();
        gload_lds16(gA + k0,      &sA[0][lofsA]);
        gload_lds16(gA + k0 + 32, &sA[1][lofsA]);
        gload_lds16(gB + k0,       &sB[0][lofsB]);
        gload_lds16(gB + k0 + 32,  &sB[1][lofsB]);
        gload_lds16(gB2 + k0,      &sB[0][lofsB + 16 * 32]);
        gload_lds16(gB2 + k0 + 32, &sB[1][lofsB + 16 * 32]);
        __syncthreads();
#pragma unroll 1
        for (int p = 0; p < 2; ++p) {
            bf16x8 af[2], bfr[4];
#pragma unroll
            for (int mt = 0; mt < 2; ++mt)
                af[mt] = *(const bf16x8*)(&sA[p][(wm + mt * 16 + q15) * 32 + koff]);
#pragma unroll
            for (int nt = 0; nt < 4; ++nt)
                bfr[nt] = *(const bf16x8*)(&sB[p][(wn + nt * 16 + q15) * 32 + koff]);
#pragma unroll
            for (int mt = 0; mt < 2; ++mt)
#pragma unroll
                for (int nt = 0; nt < 4; ++nt)
                    acc[mt][nt] = MFMA16(af[mt], bfr[nt], acc[mt][nt]);
        }
    }

    const int rq = (lane >> 4) * 4;
#pragma unroll
    for (int nt = 0; nt < 4; ++nt) {
        const int col = n0 + wn + nt * 16 + q15;
        const float bv = b2f(bias[col]);
#pragma unroll
        for (int mt = 0; mt < 2; ++mt) {
            const int row = m0 + wm + mt * 16 + rq;
            f32x4 v = acc[mt][nt];
#pragma unroll
            for (int e = 0; e < 4; ++e) {
                float val = v[e] + bv;
                if (flags & 1) val = fmaxf(val, 0.f);
                if (flags & 4) val *= QSCALE;
                const size_t o = (size_t)(row + e) * N + col;
                if (resid) val += b2f(resid[o]);
                C[o] = f2b(val);
            }
        }
    }
}

// ---------------------------------------------------------------------------
// Flash attention (no mask). Q,K: [B*S, H*R]; Vt: [B,H,R,S]; O: [B*S, H*R].
// R7: 128 Q rows per block (two 64-row halves share each staged K/V tile).
// grid 512, flat id = qt*64 + (b*16+h), qt in [0,8). Rows padded to 72.
// Q pre-scaled by QSCALE; T5 setprio around MFMA clusters (R6, +2.7us).
// ---------------------------------------------------------------------------
__global__ __launch_bounds__(256) void attn_k(
    const u16* __restrict__ Q, const u16* __restrict__ K,
    const u16* __restrict__ Vt, u16* __restrict__ O)
{
    __shared__ u16 sK[64 * 72];
    __shared__ u16 sV[64 * 72];
    __shared__ u16 sP[4][16 * 72];
    const int tid = threadIdx.x, wave = tid >> 6, lane = tid & 63;
    const int q15 = lane & 15, quad = lane >> 4;
    const int bid = blockIdx.x;
    const int g = bid & 63, qt = bid >> 6;     // qt in [0,8)
    const int h = g & 15, b = g >> 4;

    const u16* qb0 = Q + ((size_t)(b * 1024 + qt * 128 + wave * 16 + q15)) * 1024 + h * 64 + quad * 8;
    const u16* qb1 = qb0 + (size_t)64 * 1024;
    bf16x8 qa[2][2];
    qa[0][0] = *(const bf16x8*)qb0;
    qa[0][1] = *(const bf16x8*)(qb0 + 32);
    qa[1][0] = *(const bf16x8*)qb1;
    qa[1][1] = *(const bf16x8*)(qb1 + 32);

    bf16x8 vone;
#pragma unroll
    for (int i = 0; i < 8; ++i) vone[i] = (__bf16)1.0f;

    f32x4 oacc[2][4];
#pragma unroll
    for (int hh = 0; hh < 2; ++hh)
#pragma unroll
        for (int i = 0; i < 4; ++i) oacc[hh][i] = (f32x4){0.f, 0.f, 0.f, 0.f};
    f32x4 lacc[2];
    lacc[0] = (f32x4){0.f, 0.f, 0.f, 0.f};
    lacc[1] = (f32x4){0.f, 0.f, 0.f, 0.f};

    const int srow = lane >> 3, scol8 = (lane & 7) * 8;
    const u16* kg = K + ((size_t)(b * 1024 + wave * 8 + srow)) * 1024 + h * 64 + scol8;
    const u16* vg = Vt + ((size_t)((b * 16 + h) * 64 + wave * 8 + srow)) * 1024 + scol8;
    u16* lKw = sK + (wave * 8 + srow) * 72 + scol8;
    u16* lVw = sV + (wave * 8 + srow) * 72 + scol8;

    uint4 k0r = *(const uint4*)kg;
    uint4 k1r = *(const uint4*)(kg + (size_t)32 * 1024);
    uint4 v0r = *(const uint4*)vg;
    uint4 v1r = *(const uint4*)(vg + (size_t)32 * 1024);

    for (int tt = 0; tt < 16; ++tt) {
        __syncthreads();
        *(uint4*)lKw = k0r;
        *(uint4*)(lKw + 32 * 72) = k1r;
        *(uint4*)lVw = v0r;
        *(uint4*)(lVw + 32 * 72) = v1r;
        __syncthreads();
        if (tt < 15) {
            const size_t t1 = (size_t)(tt + 1) * 64;
            k0r = *(const uint4*)(kg + t1 * 1024);
            k1r = *(const uint4*)(kg + t1 * 1024 + (size_t)32 * 1024);
            v0r = *(const uint4*)(vg + t1);
            v1r = *(const uint4*)(vg + t1 + (size_t)32 * 1024);
        }

#pragma unroll
        for (int hf = 0; hf < 2; ++hf) {
            f32x4 sc[4];
            __builtin_amdgcn_s_setprio(1);
#pragma unroll
            for (int nf = 0; nf < 4; ++nf) {
                bf16x8 kb0 = *(const bf16x8*)(sK + (nf * 16 + q15) * 72 + quad * 8);
                bf16x8 kb1 = *(const bf16x8*)(sK + (nf * 16 + q15) * 72 + 32 + quad * 8);
                f32x4 t = (f32x4){0.f, 0.f, 0.f, 0.f};
                t = MFMA16(qa[hf][0], kb0, t);
                t = MFMA16(qa[hf][1], kb1, t);
                sc[nf] = t;
            }
            __builtin_amdgcn_s_setprio(0);
#pragma unroll
            for (int nf = 0; nf < 4; ++nf)
#pragma unroll
                for (int e = 0; e < 4; ++e) sc[nf][e] = fexp2(sc[nf][e]);
#pragma unroll
            for (int nf = 0; nf < 4; ++nf)
#pragma unroll
                for (int e = 0; e < 4; ++e)
                    sP[wave][(quad * 4 + e) * 72 + nf * 16 + q15] = f2b(sc[nf][e]);
            asm volatile("s_waitcnt lgkmcnt(0)" ::: "memory");
            const bf16x8 pa0 = *(const bf16x8*)(sP[wave] + q15 * 72 + quad * 8);
            const bf16x8 pa1 = *(const bf16x8*)(sP[wave] + q15 * 72 + 32 + quad * 8);
            __builtin_amdgcn_s_setprio(1);
#pragma unroll
            for (int rf = 0; rf < 4; ++rf) {
                bf16x8 vb0 = *(const bf16x8*)(sV + (rf * 16 + q15) * 72 + quad * 8);
                bf16x8 vb1 = *(const bf16x8*)(sV + (rf * 16 + q15) * 72 + 32 + quad * 8);
                oacc[hf][rf] = MFMA16(pa0, vb0, oacc[hf][rf]);
                oacc[hf][rf] = MFMA16(pa1, vb1, oacc[hf][rf]);
            }
            lacc[hf] = MFMA16(pa0, vone, lacc[hf]);
            lacc[hf] = MFMA16(pa1, vone, lacc[hf]);
            __builtin_amdgcn_s_setprio(0);
        }
    }
#pragma unroll
    for (int hf = 0; hf < 2; ++hf)
#pragma unroll
        for (int rf = 0; rf < 4; ++rf)
#pragma unroll
            for (int e = 0; e < 4; ++e) {
                const float v = oacc[hf][rf][e] / lacc[hf][e];
                const size_t row = (size_t)(b * 1024 + qt * 128 + hf * 64 + wave * 16 + quad * 4 + e);
                O[row * 1024 + h * 64 + rf * 16 + q15] = f2b(v);
            }
}

// ---------------------------------------------------------------------------
// LayerNorm over last dim (1024), eps=1e-3. One wave/row, 4 rows/block.
// ---------------------------------------------------------------------------
__global__ __launch_bounds__(256) void ln_k(
    const u16* __restrict__ y, const u16* __restrict__ g,
    const u16* __restrict__ be, void* __restrict__ out, const int* __restrict__ oflag)
{
    const int f = oflag ? *oflag : 0;
    const int tid = threadIdx.x, wave = tid >> 6, lane = tid & 63;
    const size_t row = (size_t)blockIdx.x * 4 + wave;
    const u16* p = y + row * 1024 + lane * 16;
    uint4 u0 = *(const uint4*)p;
    uint4 u1 = *(const uint4*)(p + 8);
    float v[16];
    unpack8(u0, v);
    unpack8(u1, v + 8);
    float s = 0.f, s2 = 0.f;
#pragma unroll
    for (int i = 0; i < 16; ++i) { s += v[i]; s2 += v[i] * v[i]; }
#pragma unroll
    for (int off = 1; off < 64; off <<= 1) {
        s += __shfl_xor(s, off, 64);
        s2 += __shfl_xor(s2, off, 64);
    }
    const float mean = s * (1.f / 1024.f);
    const float var = s2 * (1.f / 1024.f) - mean * mean;
    const float rstd = rsqrtf(var + 1e-3f);
    uint4 g0 = *(const uint4*)(g + lane * 16);
    uint4 g1 = *(const uint4*)(g + lane * 16 + 8);
    uint4 b0 = *(const uint4*)(be + lane * 16);
    uint4 b1 = *(const uint4*)(be + lane * 16 + 8);
    float gv[16], bv[16];
    unpack8(g0, gv); unpack8(g1, gv + 8);
    unpack8(b0, bv); unpack8(b1, bv + 8);
    float w[16];
#pragma unroll
    for (int i = 0; i < 16; ++i) w[i] = (v[i] - mean) * rstd * gv[i] + bv[i];
    if (f) {
        float* q = (float*)out + row * 1024 + lane * 16;
#pragma unroll
        for (int i = 0; i < 16; i += 4)
            *(float4*)(q + i) = make_float4(w[i], w[i + 1], w[i + 2], w[i + 3]);
    } else {
        uint4 o0, o1;
        o0.x = pack2(w[0], w[1]);   o0.y = pack2(w[2], w[3]);
        o0.z = pack2(w[4], w[5]);   o0.w = pack2(w[6], w[7]);
        o1.x = pack2(w[8], w[9]);   o1.y = pack2(w[10], w[11]);
        o1.z = pack2(w[12], w[13]); o1.w = pack2(w[14], w[15]);
        u16* q = (u16*)out + row * 1024 + lane * 16;
        *(uint4*)q = o0;
        *(uint4*)(q + 8) = o1;
    }
}

// ---------------------------------------------------------------------------
// Fused split-K reduce (3 partials) + residual + LayerNorm -> d_out.
// ---------------------------------------------------------------------------
__global__ __launch_bounds__(256) void ln3f_k(
    const float* __restrict__ p0, const float* __restrict__ p1,
    const float* __restrict__ p2,
    const u16* __restrict__ resid, const u16* __restrict__ g,
    const u16* __restrict__ be, void* __restrict__ out, const int* __restrict__ oflag)
{
    const int f = *oflag;
    const int tid = threadIdx.x, wave = tid >> 6, lane = tid & 63;
    const size_t row = (size_t)blockIdx.x * 4 + wave;
    const size_t base = row * 1024 + lane * 16;
    float v[16];
#pragma unroll
    for (int i = 0; i < 16; i += 4) {
        float4 a = *(const float4*)(p0 + base + i);
        float4 b = *(const float4*)(p1 + base + i);
        float4 c = *(const float4*)(p2 + base + i);
        v[i + 0] = a.x + b.x + c.x; v[i + 1] = a.y + b.y + c.y;
        v[i + 2] = a.z + b.z + c.z; v[i + 3] = a.w + b.w + c.w;
    }
    uint4 r0 = *(const uint4*)(resid + base);
    uint4 r1 = *(const uint4*)(resid + base + 8);
    float rv[16];
    unpack8(r0, rv); unpack8(r1, rv + 8);
#pragma unroll
    for (int i = 0; i < 16; ++i) v[i] += rv[i];
    float s = 0.f, s2 = 0.f;
#pragma unroll
    for (int i = 0; i < 16; ++i) { s += v[i]; s2 += v[i] * v[i]; }
#pragma unroll
    for (int off = 1; off < 64; off <<= 1) {
        s += __shfl_xor(s, off, 64);
        s2 += __shfl_xor(s2, off, 64);
    }
    const float mean = s * (1.f / 1024.f);
    const float var = s2 * (1.f / 1024.f) - mean * mean;
    const float rstd = rsqrtf(var + 1e-3f);
    uint4 g0 = *(const uint4*)(g + lane * 16);
    uint4 g1 = *(const uint4*)(g + lane * 16 + 8);
    uint4 b0 = *(const uint4*)(be + lane * 16);
    uint4 b1 = *(const uint4*)(be + lane * 16 + 8);
    float gv[16], bv[16];
    unpack8(g0, gv); unpack8(g1, gv + 8);
    unpack8(b0, bv); unpack8(b1, bv + 8);
    float w[16];
#pragma unroll
    for (int i = 0; i < 16; ++i) w[i] = (v[i] - mean) * rstd * gv[i] + bv[i];
    if (f) {
        float* q = (float*)out + base;
#pragma unroll
        for (int i = 0; i < 16; i += 4)
            *(float4*)(q + i) = make_float4(w[i], w[i + 1], w[i + 2], w[i + 3]);
    } else {
        uint4 o0, o1;
        o0.x = pack2(w[0], w[1]);   o0.y = pack2(w[2], w[3]);
        o0.z = pack2(w[4], w[5]);   o0.w = pack2(w[6], w[7]);
        o1.x = pack2(w[8], w[9]);   o1.y = pack2(w[10], w[11]);
        o1.z = pack2(w[12], w[13]); o1.w = pack2(w[14], w[15]);
        u16* q = (u16*)out + base;
        *(uint4*)q = o0;
        *(uint4*)(q + 8) = o1;
    }
}

// ---------------------------------------------------------------------------
extern "C" void kernel_launch(void* const* d_in, const int* in_sizes, int n_in,
                              void* d_out, int out_size, void* d_ws, size_t ws_size,
                              hipStream_t stream)
{
    (void)in_sizes; (void)n_in; (void)out_size; (void)ws_size;
    const void* x   = d_in[0];
    const void* ctx = d_in[1];

    u16* ws = (u16*)d_ws;
    const size_t MEG = 1u << 20;
    u16* wT      = ws;               // 0..16M elems: transposed weights
    u16* bufx    = ws + 16 * MEG;
    u16* bufctx  = ws + 20 * MEG;
    u16* bufq    = ws + 24 * MEG;
    u16* bufk_sa = ws + 28 * MEG;
    u16* bufvt_sa= ws + 32 * MEG;
    u16* bufk_ca = ws + 36 * MEG;
    u16* bufvt_ca= ws + 40 * MEG;
    u16* bufo    = ws + 44 * MEG;
    u16* bufln   = ws + 48 * MEG;
    u16* small   = ws + 52 * MEG;
    int* flag    = (int*)(small + 20480);
    u16* bufh    = ws + 16 * MEG;    // FFN hidden (16..32M; bufx/ctx/q/k_sa dead)
    // split-K=3 fp32 partials (each 4096x1024 f32 = 16 MB = 8M u16):
    //  p0: 32..40M (bufvt_sa dead), p1: 40..48M (bufvt_ca/bufo dead),
    //  p2: 4..12M (wT[4..12M] all consumed before FFN2; wT[12..16M] stays live)
    float* part0 = (float*)(ws + 32 * MEG);
    float* part1 = (float*)(ws + 40 * MEG);
    float* part2 = (float*)(ws + 4 * MEG);

    const int O_SABQ = 0,    O_SABK = 1024, O_SABV = 2048;
    const int O_CABK = 3072, O_CABV = 4096, O_CABQ = 5120;
    const int O_SABO = 6144, O_CABO = 7168;
    const int O_L1G = 8192,  O_L1B = 9216,  O_L2G = 10240, O_L2B = 11264;
    const int O_L3G = 12288, O_L3B = 13312, O_FB1 = 14336, O_FB2 = 18432;

    PtrTab tab;
    const void* sp[16] = { d_in[3], d_in[5], d_in[7], d_in[13], d_in[15], d_in[11],
                           d_in[9], d_in[17],
                           d_in[18], d_in[19], d_in[20], d_in[21], d_in[22], d_in[23],
                           d_in[25], d_in[27] };
    const int so[16] = { O_SABQ, O_SABK, O_SABV, O_CABK, O_CABV, O_CABQ, O_SABO, O_CABO,
                         O_L1G, O_L1B, O_L2G, O_L2B, O_L3G, O_L3B, O_FB1, O_FB2 };
    const int sc[16] = { 1024, 1024, 1024, 1024, 1024, 1024, 1024, 1024,
                         1024, 1024, 1024, 1024, 1024, 1024, 4096, 1024 };
    for (int i = 0; i < 16; ++i) { tab.p[i] = sp[i]; tab.off[i] = so[i]; tab.cnt[i] = sc[i]; }

    PtrTab tab6;
    const void* wp[6] = { d_in[2], d_in[4], d_in[6], d_in[12], d_in[14], d_in[10] };
    for (int i = 0; i < 6; ++i) tab6.p[i] = wp[i];

    const dim3 blk(256);
    const dim3 blk8(512);
    const dim3 gN1(64, 8);

    // ---- dtype detect + single fused prep dispatch (R8: 8 launches -> 2) ----
    detect_k<<<1, blk, 0, stream>>>((const u32*)x, flag);
    prep_k<<<dim3(8208), blk, 0, stream>>>(x, ctx, bufx, bufctx, tab, small, tab6, wT,
                                           d_in[8], d_in[16], d_in[24], d_in[26], flag);

    // ---- fused projections (SA-Q pre-scaled by QSCALE) ----
    gemm_qkv_k<<<dim3(40, 32), blk, 0, stream>>>(bufx, bufctx, wT, small,
                                                 bufq, bufk_sa, bufvt_sa, bufk_ca, bufvt_ca);

    // ---- self-attention (128 Q rows/block -> grid 512) ----
    attn_k<<<dim3(512), blk, 0, stream>>>(bufq, bufk_sa, bufvt_sa, bufo);
    gemm_n1k<<<gN1, blk, 0, stream>>>(bufo, wT + 6 * MEG, small + O_SABO, bufx,
                                      bufq, 4096, 1024, 1024, 0);
    ln_k<<<dim3(1024), blk, 0, stream>>>(bufq, small + O_L1G, small + O_L1B, bufln, nullptr);

    // ---- cross-attention (CA-Q pre-scaled via flags|4) ----
    gemm_n1k<<<gN1, blk, 0, stream>>>(bufln, wT + 5 * MEG, small + O_CABQ, nullptr,
                                      bufq, 4096, 1024, 1024, 4);
    attn_k<<<dim3(512), blk, 0, stream>>>(bufq, bufk_ca, bufvt_ca, bufo);
    gemm_n1k<<<gN1, blk, 0, stream>>>(bufo, wT + 7 * MEG, small + O_CABO, bufln,
                                      bufq, 4096, 1024, 1024, 0);
    ln_k<<<dim3(1024), blk, 0, stream>>>(bufq, small + O_L2G, small + O_L2B, bufln, nullptr);

    // ---- FFN (256^2 8-phase; FFN2 split-K=3 + fused reduce/LN) ----
    gemm8p_ffn1<<<dim3(16, 16), blk8, 0, stream>>>(bufln, wT + 8 * MEG, small + O_FB1,
                                                   bufh, 4096, 16);
    gemm8p_ffn2<<<dim3(4, 16, 3), blk8, 0, stream>>>(bufh, wT + 12 * MEG, small + O_FB2,
                                                     part0, part1, part2);
    ln3f_k<<<dim3(1024), blk, 0, stream>>>(part0, part1, part2, bufln,
                                           small + O_L3G, small + O_L3B, d_out, flag);
}